// Round 2
// 9733.979 us; speedup vs baseline: 4.0955x; 4.0955x over previous
//
#include <hip/hip_runtime.h>
#include <cmath>

// Problem constants
#define BATCH 8
#define SEQ   512
#define EMB   512
#define HEADS 8
#define DK    64
#define FF    2048
#define VOCAB 32000
#define TOK   (BATCH * SEQ)   // 4096 rows
#define INV_SCALE 0.125f      // 1/sqrt(64)

// ---------------------------------------------------------------------------
// Embedding lookup + positional encoding (faithful f32 like the jax ref)
// ---------------------------------------------------------------------------
__global__ __launch_bounds__(256) void embed_pe_kernel(
    const int* __restrict__ tok, const float* __restrict__ table,
    float* __restrict__ out)
{
    int idx = blockIdx.x * 256 + threadIdx.x;      // < TOK*EMB = 2M
    int d   = idx & (EMB - 1);
    int row = idx >> 9;                            // EMB = 512 = 2^9
    int s   = row & (SEQ - 1);                     // SEQ = 512
    float p   = powf(10000.0f, (2.0f * (float)d) * (1.0f / (float)EMB));
    float ang = (float)s / p;
    float pe  = ((d & 1) == 0) ? sinf(ang) : cosf(ang);
    out[idx] = table[(size_t)tok[row] * EMB + d] + pe;
}

// ---------------------------------------------------------------------------
// Generic GEMM: C[M,N] = A[M,K] @ W[N,K]^T (+ bias[n]) (optional ReLU)
// 64x64 tile, BK=16, 256 threads, 4x4 accum per thread. All dims multiples.
// ---------------------------------------------------------------------------
template<bool HASBIAS, bool RELU>
__global__ __launch_bounds__(256) void gemm_tn(
    const float* __restrict__ A, const float* __restrict__ W,
    const float* __restrict__ bias, float* __restrict__ C,
    int M, int N, int K)
{
    __shared__ float As[16][64];
    __shared__ float Bs[16][64];
    const int tid = threadIdx.x;
    const int tx  = tid & 15;          // n-direction
    const int ty  = tid >> 4;          // m-direction
    const int m0  = blockIdx.y << 6;
    const int n0  = blockIdx.x << 6;
    const int lrow = tid >> 2;         // 0..63
    const int lcol = (tid & 3) << 2;   // 0,4,8,12

    const float* Aload = A + (size_t)(m0 + lrow) * K + lcol;
    const float* Wload = W + (size_t)(n0 + lrow) * K + lcol;

    float acc[4][4] = {};

    for (int k0 = 0; k0 < K; k0 += 16) {
        float4 a4 = *(const float4*)(Aload + k0);
        float4 w4 = *(const float4*)(Wload + k0);
        As[lcol + 0][lrow] = a4.x; As[lcol + 1][lrow] = a4.y;
        As[lcol + 2][lrow] = a4.z; As[lcol + 3][lrow] = a4.w;
        Bs[lcol + 0][lrow] = w4.x; Bs[lcol + 1][lrow] = w4.y;
        Bs[lcol + 2][lrow] = w4.z; Bs[lcol + 3][lrow] = w4.w;
        __syncthreads();
#pragma unroll
        for (int kk = 0; kk < 16; ++kk) {
            float4 av = *(const float4*)&As[kk][ty << 2];
            float4 bv = *(const float4*)&Bs[kk][tx << 2];
            float a[4] = {av.x, av.y, av.z, av.w};
            float b[4] = {bv.x, bv.y, bv.z, bv.w};
#pragma unroll
            for (int i = 0; i < 4; ++i)
#pragma unroll
                for (int j = 0; j < 4; ++j)
                    acc[i][j] = fmaf(a[i], b[j], acc[i][j]);
        }
        __syncthreads();
    }

#pragma unroll
    for (int i = 0; i < 4; ++i) {
        const int m = m0 + (ty << 2) + i;
#pragma unroll
        for (int j = 0; j < 4; ++j) {
            const int n = n0 + (tx << 2) + j;
            float v = acc[i][j];
            if (HASBIAS) v += bias[n];
            if (RELU)    v = fmaxf(v, 0.0f);
            C[(size_t)m * N + n] = v;
        }
    }
}

// ---------------------------------------------------------------------------
// Flash-style tiled attention.
// One block per (b, h, 64-row q-tile). 256 threads, 4x4 micro-tiles.
// Scores S = (Q K^T + mask) * INV_SCALE computed 64x64 at a time from LDS;
// online softmax (running m,l per q-row in registers, shfl row-reductions);
// P staged in LDS (aliases dead K buffer) for the PV matmul.
// Q/K/V given by base ptr + row stride + head col stride (folded host-side).
// ---------------------------------------------------------------------------
__global__ __launch_bounds__(256) void attn_tile_kernel(
    const float* __restrict__ Qb, int q_rs, int q_hs,
    const float* __restrict__ Kb, int k_rs, int k_hs,
    const float* __restrict__ Vb, int v_rs, int v_hs,
    const float* __restrict__ addmask, int causal,
    float* __restrict__ ctx, int SQ, int SK)
{
    const int qt = blockIdx.x, h = blockIdx.y, b = blockIdx.z;
    const int t  = threadIdx.x;
    const int q0 = qt << 6;

    // pad 68: float4-aligned rows, bank-rotating (2-way max)
    __shared__ float sQT[64][68];   // Q transposed: [d][q]
    __shared__ float sKP[64][68];   // K transposed [d][k], then P [k][q]
    __shared__ float sV [64][68];   // V natural:   [k][d]

    const int lr = t & 63;          // row this thread loads
    const int dc = (t >> 6) << 4;   // 16-float chunk (one 64B line/thread)

    // ---- load Q tile, transposed ----
    {
        const float* Qrow = Qb + (size_t)(b * SQ + q0 + lr) * q_rs + h * q_hs + dc;
#pragma unroll
        for (int u = 0; u < 4; ++u) {
            float4 v = *(const float4*)(Qrow + u * 4);
            sQT[dc + u * 4 + 0][lr] = v.x;
            sQT[dc + u * 4 + 1][lr] = v.y;
            sQT[dc + u * 4 + 2][lr] = v.z;
            sQT[dc + u * 4 + 3][lr] = v.w;
        }
    }

    const int tx = t & 15;          // k-cols (scores) / d-cols (output)
    const int ty = t >> 4;          // q-rows

    float M[4], L[4], o[4][4];
#pragma unroll
    for (int i = 0; i < 4; ++i) {
        M[i] = -INFINITY; L[i] = 0.0f;
#pragma unroll
        for (int j = 0; j < 4; ++j) o[i][j] = 0.0f;
    }

    const int nkt = causal ? (qt + 1) : (SK >> 6);

    for (int kt = 0; kt < nkt; ++kt) {
        const int k0 = kt << 6;
        __syncthreads();   // prior PV reads of sKP/sV done before overwrite

        // ---- load K (transposed) and V tiles ----
        {
            const float* Krow = Kb + (size_t)(b * SK + k0 + lr) * k_rs + h * k_hs + dc;
            const float* Vrow = Vb + (size_t)(b * SK + k0 + lr) * v_rs + h * v_hs + dc;
#pragma unroll
            for (int u = 0; u < 4; ++u) {
                float4 kv = *(const float4*)(Krow + u * 4);
                sKP[dc + u * 4 + 0][lr] = kv.x;
                sKP[dc + u * 4 + 1][lr] = kv.y;
                sKP[dc + u * 4 + 2][lr] = kv.z;
                sKP[dc + u * 4 + 3][lr] = kv.w;
                *(float4*)&sV[lr][dc + u * 4] = *(const float4*)(Vrow + u * 4);
            }
        }
        __syncthreads();

        // ---- scores: s[i][j] = sum_d Q[q0+ty4+i][d] * K[k0+tx4+j][d] ----
        float s[4][4] = {};
#pragma unroll 16
        for (int d = 0; d < 64; ++d) {
            float4 aq = *(const float4*)&sQT[d][ty << 2];
            float4 bk = *(const float4*)&sKP[d][tx << 2];
            float a[4] = {aq.x, aq.y, aq.z, aq.w};
            float bb[4] = {bk.x, bk.y, bk.z, bk.w};
#pragma unroll
            for (int i = 0; i < 4; ++i)
#pragma unroll
                for (int j = 0; j < 4; ++j)
                    s[i][j] = fmaf(a[i], bb[j], s[i][j]);
        }

        // ---- mask + scale ----
#pragma unroll
        for (int j = 0; j < 4; ++j) {
            const int k = k0 + (tx << 2) + j;
            const float m = addmask ? addmask[(size_t)b * SK + k] : 0.0f;
#pragma unroll
            for (int i = 0; i < 4; ++i) {
                float sv = (s[i][j] + m) * INV_SCALE;
                if (causal && k > q0 + (ty << 2) + i) sv = -INFINITY;
                s[i][j] = sv;
            }
        }

        // ---- row max across the 16 tx lanes ----
        float mx[4];
#pragma unroll
        for (int i = 0; i < 4; ++i)
            mx[i] = fmaxf(fmaxf(s[i][0], s[i][1]), fmaxf(s[i][2], s[i][3]));
#pragma unroll
        for (int off = 1; off < 16; off <<= 1) {
#pragma unroll
            for (int i = 0; i < 4; ++i)
                mx[i] = fmaxf(mx[i], __shfl_xor(mx[i], off, 64));
        }

        // ---- online softmax update ----
        float al[4];
#pragma unroll
        for (int i = 0; i < 4; ++i) {
            const float Mn = fmaxf(M[i], mx[i]);
            al[i] = expf(M[i] - Mn);   // first tile: exp(-inf)=0
            M[i]  = Mn;
        }
        float rs[4] = {};
#pragma unroll
        for (int i = 0; i < 4; ++i) {
#pragma unroll
            for (int j = 0; j < 4; ++j) {
                const float p = expf(s[i][j] - M[i]);  // -inf -> 0
                s[i][j] = p;
                rs[i] += p;
            }
        }
#pragma unroll
        for (int off = 1; off < 16; off <<= 1) {
#pragma unroll
            for (int i = 0; i < 4; ++i)
                rs[i] += __shfl_xor(rs[i], off, 64);
        }
#pragma unroll
        for (int i = 0; i < 4; ++i) {
            L[i] = L[i] * al[i] + rs[i];
#pragma unroll
            for (int j = 0; j < 4; ++j) o[i][j] *= al[i];
        }

        // ---- stage P into LDS as [k][q] (aliases dead K buffer) ----
        __syncthreads();   // all score-reads of sKP done
#pragma unroll
        for (int j = 0; j < 4; ++j)
#pragma unroll
            for (int i = 0; i < 4; ++i)
                sKP[(tx << 2) + j][(ty << 2) + i] = s[i][j];
        __syncthreads();

        // ---- PV: o[i][j] += P[kk][q=ty4+i] * V[kk][d=tx4+j] ----
#pragma unroll 16
        for (int kk = 0; kk < 64; ++kk) {
            float4 pa = *(const float4*)&sKP[kk][ty << 2];
            float4 vb = *(const float4*)&sV[kk][tx << 2];
            float a[4] = {pa.x, pa.y, pa.z, pa.w};
            float bb[4] = {vb.x, vb.y, vb.z, vb.w};
#pragma unroll
            for (int i = 0; i < 4; ++i)
#pragma unroll
                for (int j = 0; j < 4; ++j)
                    o[i][j] = fmaf(a[i], bb[j], o[i][j]);
        }
    }

    // ---- epilogue: ctx[q][h*64+d] = o / L ----
#pragma unroll
    for (int i = 0; i < 4; ++i) {
        const float inv = 1.0f / L[i];
        float4 w;
        w.x = o[i][0] * inv; w.y = o[i][1] * inv;
        w.z = o[i][2] * inv; w.w = o[i][3] * inv;
        const int q = q0 + (ty << 2) + i;
        *(float4*)&ctx[(size_t)(b * SQ + q) * EMB + h * DK + (tx << 2)] = w;
    }
}

// ---------------------------------------------------------------------------
// x[row,:] = LayerNorm(x[row,:] + delta[row,:]) * g + b   (row length 512)
// ---------------------------------------------------------------------------
__global__ __launch_bounds__(256) void add_ln_kernel(
    float* __restrict__ x, const float* __restrict__ delta,
    const float* __restrict__ g, const float* __restrict__ b)
{
    const int row = blockIdx.x;
    const int t = threadIdx.x;
    __shared__ float red[256];
    const size_t base = (size_t)row * EMB;

    float v0 = x[base + t]       + delta[base + t];
    float v1 = x[base + 256 + t] + delta[base + 256 + t];

    red[t] = v0 + v1; __syncthreads();
    for (int o = 128; o > 0; o >>= 1) {
        if (t < o) red[t] += red[t + o];
        __syncthreads();
    }
    const float mean = red[0] * (1.0f / (float)EMB);
    __syncthreads();

    const float a0 = v0 - mean, a1 = v1 - mean;
    red[t] = a0 * a0 + a1 * a1; __syncthreads();
    for (int o = 128; o > 0; o >>= 1) {
        if (t < o) red[t] += red[t + o];
        __syncthreads();
    }
    const float inv = 1.0f / sqrtf(red[0] * (1.0f / (float)EMB) + 1e-5f);

    x[base + t]       = a0 * inv * g[t]       + b[t];
    x[base + 256 + t] = a1 * inv * g[256 + t] + b[256 + t];
}

// ---------------------------------------------------------------------------
// Row softmax over VOCAB (in place). One block per row, online max/sum.
// ---------------------------------------------------------------------------
__global__ __launch_bounds__(256) void softmax_vocab_kernel(float* __restrict__ X)
{
    const int row = blockIdx.x;
    const int t = threadIdx.x;
    __shared__ float rm[256], rs[256];
    float* x = X + (size_t)row * VOCAB;

    float m = -INFINITY, s = 0.0f;
    for (int k = t; k < VOCAB; k += 256) {
        float v = x[k];
        if (v > m) { s = s * expf(m - v) + 1.0f; m = v; }
        else       { s += expf(v - m); }
    }
    rm[t] = m; rs[t] = s; __syncthreads();
    for (int o = 128; o > 0; o >>= 1) {
        if (t < o) {
            float m1 = rm[t], m2 = rm[t + o];
            float s1 = rs[t], s2 = rs[t + o];
            float MM = fmaxf(m1, m2);
            rs[t] = s1 * expf(m1 - MM) + s2 * expf(m2 - MM);
            rm[t] = MM;
        }
        __syncthreads();
    }
    const float M = rm[0];
    const float inv = 1.0f / rs[0];
    for (int k = t; k < VOCAB; k += 256) x[k] = expf(x[k] - M) * inv;
}

// ---------------------------------------------------------------------------
// Host orchestration
// ---------------------------------------------------------------------------
static inline void launch_gemm(const float* A, const float* W, const float* bias,
                               float* C, int M, int N, int K, bool relu,
                               hipStream_t stream)
{
    dim3 grid((unsigned)(N / 64), (unsigned)(M / 64));
    if (bias) {
        if (relu) gemm_tn<true, true ><<<grid, 256, 0, stream>>>(A, W, bias, C, M, N, K);
        else      gemm_tn<true, false><<<grid, 256, 0, stream>>>(A, W, bias, C, M, N, K);
    } else {
        gemm_tn<false, false><<<grid, 256, 0, stream>>>(A, W, nullptr, C, M, N, K);
    }
}

extern "C" void kernel_launch(void* const* d_in, const int* in_sizes, int n_in,
                              void* d_out, int out_size, void* d_ws, size_t ws_size,
                              hipStream_t stream)
{
    const int*   enc      = (const int*)  d_in[0];
    const int*   dec      = (const int*)  d_in[1];
    const float* enc_mask = (const float*)d_in[2];
    const float* dec_mask = (const float*)d_in[3];
    // d_in[4], d_in[5]: enc_num/dec_num == 6 (compile-time constants)
    const float* emb    = (const float*)d_in[6];
    const float* w_qkv  = (const float*)d_in[7];
    const float* w_lin  = (const float*)d_in[8];
    const float* b_lin  = (const float*)d_in[9];
    const float* w_ff1  = (const float*)d_in[10];
    const float* b_ff1  = (const float*)d_in[11];
    const float* w_ff2  = (const float*)d_in[12];
    const float* b_ff2  = (const float*)d_in[13];
    const float* w_out  = (const float*)d_in[14];
    const float* b_out  = (const float*)d_in[15];
    const float* ln_e1g = (const float*)d_in[16];
    const float* ln_e1b = (const float*)d_in[17];
    const float* ln_e2g = (const float*)d_in[18];
    const float* ln_e2b = (const float*)d_in[19];
    const float* ln_d1g = (const float*)d_in[20];
    const float* ln_d1b = (const float*)d_in[21];
    const float* ln_d2g = (const float*)d_in[22];
    const float* ln_d2b = (const float*)d_in[23];
    const float* ln_d3g = (const float*)d_in[24];
    const float* ln_d3b = (const float*)d_in[25];

    float* out = (float*)d_out;

    // Workspace layout. x_d must survive until the final vocab GEMM, so it
    // always lives in d_ws. Everything else is dead before the final GEMM
    // and can fall back into d_out if d_ws is small.
    const size_t sz_x   = (size_t)TOK * EMB * sizeof(float);     // 8 MB
    const size_t sz_qkv = (size_t)TOK * 3 * EMB * sizeof(float); // 25 MB
    const size_t sz_ff  = (size_t)TOK * FF * sizeof(float);      // 33.5 MB
    const size_t need   = 2 * sz_x + 2 * sz_qkv + 2 * sz_x + sz_ff;

    char* wsp = (char*)d_ws;
    float* x_d_buf = (float*)wsp; wsp += sz_x;
    float *x_e, *qkv, *ekv, *ctxb, *tmpb, *ffb;
    if (ws_size >= need) {
        x_e  = (float*)wsp; wsp += sz_x;
        qkv  = (float*)wsp; wsp += sz_qkv;
        ekv  = (float*)wsp; wsp += sz_qkv;
        ctxb = (float*)wsp; wsp += sz_x;
        tmpb = (float*)wsp; wsp += sz_x;
        ffb  = (float*)wsp;
    } else {
        char* op = (char*)d_out;   // scratch inside d_out; dead before final GEMM
        x_e  = (float*)op; op += sz_x;
        qkv  = (float*)op; op += sz_qkv;
        ekv  = (float*)op; op += sz_qkv;
        ctxb = (float*)op; op += sz_x;
        tmpb = (float*)op; op += sz_x;
        ffb  = (float*)op;
    }

    const dim3 attn_grid(SEQ / 64, HEADS, BATCH);   // (8, 8, 8)
    const int  embed_blocks = (TOK * EMB) / 256;

    // Embedding + positional encoding
    embed_pe_kernel<<<embed_blocks, 256, 0, stream>>>(enc, emb, x_e);
    embed_pe_kernel<<<embed_blocks, 256, 0, stream>>>(dec, emb, x_d_buf);

    // ---------------- Encoder (6 layers) ----------------
    for (int l = 0; l < 6; ++l) {
        launch_gemm(x_e, w_qkv, nullptr, qkv, TOK, 3 * EMB, EMB, false, stream);
        attn_tile_kernel<<<attn_grid, 256, 0, stream>>>(
            qkv,        3 * EMB, 3 * DK,       // Q: col h*192 + d
            qkv + DK,   3 * EMB, 3 * DK,       // K: col h*192 + 64 + d
            qkv + 2*DK, 3 * EMB, 3 * DK,       // V: col h*192 + 128 + d
            enc_mask, 0, ctxb, SEQ, SEQ);
        launch_gemm(ctxb, w_lin, b_lin, tmpb, TOK, EMB, EMB, false, stream);
        add_ln_kernel<<<TOK, 256, 0, stream>>>(x_e, tmpb, ln_e1g, ln_e1b);
        launch_gemm(x_e, w_ff1, b_ff1, ffb, TOK, FF, EMB, true, stream);
        launch_gemm(ffb, w_ff2, b_ff2, tmpb, TOK, EMB, FF, false, stream);
        add_ln_kernel<<<TOK, 256, 0, stream>>>(x_e, tmpb, ln_e2g, ln_e2b);
    }

    // Encoder K/V for cross-attention
    launch_gemm(x_e, w_qkv, nullptr, ekv, TOK, 3 * EMB, EMB, false, stream);

    // ---------------- Decoder (6 layers) ----------------
    for (int l = 0; l < 6; ++l) {
        // self-attention (causal + dec_mask)
        launch_gemm(x_d_buf, w_qkv, nullptr, qkv, TOK, 3 * EMB, EMB, false, stream);
        attn_tile_kernel<<<attn_grid, 256, 0, stream>>>(
            qkv,        3 * EMB, 3 * DK,
            qkv + DK,   3 * EMB, 3 * DK,
            qkv + 2*DK, 3 * EMB, 3 * DK,
            dec_mask, 1, ctxb, SEQ, SEQ);
        launch_gemm(ctxb, w_lin, b_lin, tmpb, TOK, EMB, EMB, false, stream);
        add_ln_kernel<<<TOK, 256, 0, stream>>>(x_d_buf, tmpb, ln_d1g, ln_d1b);

        // cross-attention: dq = (x_d @ w_qkv.T)[:, :512] — head stride 64
        launch_gemm(x_d_buf, w_qkv, nullptr, qkv, TOK, EMB, EMB, false, stream);
        attn_tile_kernel<<<attn_grid, 256, 0, stream>>>(
            qkv,          EMB,     DK,          // dq: col h*64 + d, row stride 512
            ekv + DK,     3 * EMB, 3 * DK,      // ek
            ekv + 2*DK,   3 * EMB, 3 * DK,      // ev
            enc_mask, 0, ctxb, SEQ, SEQ);
        launch_gemm(ctxb, w_lin, b_lin, tmpb, TOK, EMB, EMB, false, stream);
        add_ln_kernel<<<TOK, 256, 0, stream>>>(x_d_buf, tmpb, ln_d2g, ln_d2b);

        // FFN
        launch_gemm(x_d_buf, w_ff1, b_ff1, ffb, TOK, FF, EMB, true, stream);
        launch_gemm(ffb, w_ff2, b_ff2, tmpb, TOK, EMB, FF, false, stream);
        add_ln_kernel<<<TOK, 256, 0, stream>>>(x_d_buf, tmpb, ln_d3g, ln_d3b);
    }

    // ---------------- Output projection + softmax ----------------
    launch_gemm(x_d_buf, w_out, b_out, out, TOK, VOCAB, EMB, false, stream);
    softmax_vocab_kernel<<<TOK, 256, 0, stream>>>(out);
}

// Round 3
// 8310.218 us; speedup vs baseline: 4.7971x; 1.1713x over previous
//
#include <hip/hip_runtime.h>
#include <cmath>

// Problem constants
#define BATCH 8
#define SEQ   512
#define EMB   512
#define HEADS 8
#define DK    64
#define FF    2048
#define VOCAB 32000
#define TOK   (BATCH * SEQ)   // 4096 rows
#define INV_SCALE 0.125f      // 1/sqrt(64)

typedef __attribute__((ext_vector_type(8))) short bf16x8;
typedef __attribute__((ext_vector_type(4))) float f32x4;

// ---------------------------------------------------------------------------
// Embedding lookup + positional encoding (faithful f32 like the jax ref)
// ---------------------------------------------------------------------------
__global__ __launch_bounds__(256) void embed_pe_kernel(
    const int* __restrict__ tok, const float* __restrict__ table,
    float* __restrict__ out)
{
    int idx = blockIdx.x * 256 + threadIdx.x;      // < TOK*EMB = 2M
    int d   = idx & (EMB - 1);
    int row = idx >> 9;                            // EMB = 512 = 2^9
    int s   = row & (SEQ - 1);                     // SEQ = 512
    float p   = powf(10000.0f, (2.0f * (float)d) * (1.0f / (float)EMB));
    float ang = (float)s / p;
    float pe  = ((d & 1) == 0) ? sinf(ang) : cosf(ang);
    out[idx] = table[(size_t)tok[row] * EMB + d] + pe;
}

// ---------------------------------------------------------------------------
// f32 -> bf16 cast (RNE), 8 elements per thread. n8 = count/8.
// ---------------------------------------------------------------------------
__global__ __launch_bounds__(256) void cast_f32_to_bf16(
    const float* __restrict__ in, unsigned short* __restrict__ out, int n8)
{
    int i = blockIdx.x * 256 + threadIdx.x;
    if (i >= n8) return;
    const float4* p = (const float4*)(in + (size_t)i * 8);
    float4 f0 = p[0], f1 = p[1];
    float v[8] = {f0.x, f0.y, f0.z, f0.w, f1.x, f1.y, f1.z, f1.w};
    union { unsigned short u[8]; int4 v4; } r;
#pragma unroll
    for (int j = 0; j < 8; ++j) {
        unsigned int u = __float_as_uint(v[j]);
        r.u[j] = (unsigned short)((u + 0x7FFFu + ((u >> 16) & 1u)) >> 16);
    }
    *(int4*)(out + (size_t)i * 8) = r.v4;
}

// ---------------------------------------------------------------------------
// bf16 MFMA GEMM: C[M,N] = A[M,K] @ B[N,K]^T + bias (f32 out).
// 128x128 tile, BK=64, 256 threads = 4 waves in 2x2 grid (64x64 per wave).
// mfma_f32_16x16x32_bf16; LDS rows padded to 72 bf16 (conflict-free b128).
// ---------------------------------------------------------------------------
#define MF_LDA 72
__global__ __launch_bounds__(256) void gemm_bf16_mfma(
    const unsigned short* __restrict__ A,   // [M][K] bf16
    const unsigned short* __restrict__ B,   // [N][K] bf16
    const float* __restrict__ bias,         // [N] or null
    float* __restrict__ C, int M, int N, int K)
{
    __shared__ unsigned short As[128 * MF_LDA];
    __shared__ unsigned short Bs[128 * MF_LDA];
    const int tid  = threadIdx.x;
    const int m0   = blockIdx.y << 7;
    const int n0   = blockIdx.x << 7;
    const int wave = tid >> 6;
    const int lane = tid & 63;
    const int wm   = (wave >> 1) << 6;   // wave row offset
    const int wn   = (wave & 1) << 6;    // wave col offset
    const int l15  = lane & 15;
    const int lg   = lane >> 4;          // 0..3

    f32x4 acc[4][4] = {};

    for (int k0 = 0; k0 < K; k0 += 64) {
        __syncthreads();   // previous tile's fragment reads done
#pragma unroll
        for (int it = 0; it < 4; ++it) {
            const int c   = it * 256 + tid;   // 0..1023 16B-chunks
            const int row = c >> 3;           // 0..127
            const int kc  = c & 7;            // 16B chunk within 64-wide k
            *(int4*)&As[row * MF_LDA + kc * 8] =
                *(const int4*)&A[(size_t)(m0 + row) * K + k0 + kc * 8];
            *(int4*)&Bs[row * MF_LDA + kc * 8] =
                *(const int4*)&B[(size_t)(n0 + row) * K + k0 + kc * 8];
        }
        __syncthreads();

#pragma unroll
        for (int ks = 0; ks < 2; ++ks) {
            const int kch = ks * 4 + lg;      // 16B chunk index in k
            bf16x8 af[4], bfr[4];
#pragma unroll
            for (int mi = 0; mi < 4; ++mi)
                af[mi] = *(const bf16x8*)&As[(wm + mi * 16 + l15) * MF_LDA + kch * 8];
#pragma unroll
            for (int ni = 0; ni < 4; ++ni)
                bfr[ni] = *(const bf16x8*)&Bs[(wn + ni * 16 + l15) * MF_LDA + kch * 8];
#pragma unroll
            for (int mi = 0; mi < 4; ++mi)
#pragma unroll
                for (int ni = 0; ni < 4; ++ni)
                    acc[mi][ni] = __builtin_amdgcn_mfma_f32_16x16x32_bf16(
                        af[mi], bfr[ni], acc[mi][ni], 0, 0, 0);
        }
    }

    // C/D layout (m89-verified): col = lane&15 (N), row = (lane>>4)*4 + r (M)
#pragma unroll
    for (int mi = 0; mi < 4; ++mi) {
        const int mb = m0 + wm + mi * 16 + lg * 4;
#pragma unroll
        for (int ni = 0; ni < 4; ++ni) {
            const int n = n0 + wn + ni * 16 + l15;
            const float bv = bias ? bias[n] : 0.0f;
#pragma unroll
            for (int r = 0; r < 4; ++r)
                C[(size_t)(mb + r) * N + n] = acc[mi][ni][r] + bv;
        }
    }
}

// ---------------------------------------------------------------------------
// Generic GEMM: C[M,N] = A[M,K] @ W[N,K]^T (+ bias[n]) (optional ReLU)
// 64x64 tile, BK=16, 256 threads, 4x4 accum per thread. All dims multiples.
// ---------------------------------------------------------------------------
template<bool HASBIAS, bool RELU>
__global__ __launch_bounds__(256) void gemm_tn(
    const float* __restrict__ A, const float* __restrict__ W,
    const float* __restrict__ bias, float* __restrict__ C,
    int M, int N, int K)
{
    __shared__ float As[16][64];
    __shared__ float Bs[16][64];
    const int tid = threadIdx.x;
    const int tx  = tid & 15;          // n-direction
    const int ty  = tid >> 4;          // m-direction
    const int m0  = blockIdx.y << 6;
    const int n0  = blockIdx.x << 6;
    const int lrow = tid >> 2;         // 0..63
    const int lcol = (tid & 3) << 2;   // 0,4,8,12

    const float* Aload = A + (size_t)(m0 + lrow) * K + lcol;
    const float* Wload = W + (size_t)(n0 + lrow) * K + lcol;

    float acc[4][4] = {};

    for (int k0 = 0; k0 < K; k0 += 16) {
        float4 a4 = *(const float4*)(Aload + k0);
        float4 w4 = *(const float4*)(Wload + k0);
        As[lcol + 0][lrow] = a4.x; As[lcol + 1][lrow] = a4.y;
        As[lcol + 2][lrow] = a4.z; As[lcol + 3][lrow] = a4.w;
        Bs[lcol + 0][lrow] = w4.x; Bs[lcol + 1][lrow] = w4.y;
        Bs[lcol + 2][lrow] = w4.z; Bs[lcol + 3][lrow] = w4.w;
        __syncthreads();
#pragma unroll
        for (int kk = 0; kk < 16; ++kk) {
            float4 av = *(const float4*)&As[kk][ty << 2];
            float4 bv = *(const float4*)&Bs[kk][tx << 2];
            float a[4] = {av.x, av.y, av.z, av.w};
            float b[4] = {bv.x, bv.y, bv.z, bv.w};
#pragma unroll
            for (int i = 0; i < 4; ++i)
#pragma unroll
                for (int j = 0; j < 4; ++j)
                    acc[i][j] = fmaf(a[i], b[j], acc[i][j]);
        }
        __syncthreads();
    }

#pragma unroll
    for (int i = 0; i < 4; ++i) {
        const int m = m0 + (ty << 2) + i;
#pragma unroll
        for (int j = 0; j < 4; ++j) {
            const int n = n0 + (tx << 2) + j;
            float v = acc[i][j];
            if (HASBIAS) v += bias[n];
            if (RELU)    v = fmaxf(v, 0.0f);
            C[(size_t)m * N + n] = v;
        }
    }
}

// ---------------------------------------------------------------------------
// Big-N GEMM: 128x128 tile, BK=16, 256 threads, 8x8 accum per thread.
// ---------------------------------------------------------------------------
template<bool HASBIAS, bool RELU>
__global__ __launch_bounds__(256) void gemm_tn_128(
    const float* __restrict__ A, const float* __restrict__ W,
    const float* __restrict__ bias, float* __restrict__ C,
    int M, int N, int K)
{
    __shared__ float As[16][132];
    __shared__ float Bs[16][132];
    const int tid = threadIdx.x;
    const int tx  = tid & 15;          // n-direction (16 x 8 = 128)
    const int ty  = tid >> 4;          // m-direction (16 x 8 = 128)
    const int m0  = blockIdx.y << 7;
    const int n0  = blockIdx.x << 7;
    const int lrow = tid >> 1;         // 0..127
    const int lcol = (tid & 1) << 3;   // 0 or 8

    const float* Aload = A + (size_t)(m0 + lrow) * K + lcol;
    const float* Wload = W + (size_t)(n0 + lrow) * K + lcol;

    float acc[8][8] = {};

    for (int k0 = 0; k0 < K; k0 += 16) {
        float4 a0 = *(const float4*)(Aload + k0);
        float4 a1 = *(const float4*)(Aload + k0 + 4);
        float4 w0 = *(const float4*)(Wload + k0);
        float4 w1 = *(const float4*)(Wload + k0 + 4);
        __syncthreads();   // previous iter's reads done
        As[lcol + 0][lrow] = a0.x; As[lcol + 1][lrow] = a0.y;
        As[lcol + 2][lrow] = a0.z; As[lcol + 3][lrow] = a0.w;
        As[lcol + 4][lrow] = a1.x; As[lcol + 5][lrow] = a1.y;
        As[lcol + 6][lrow] = a1.z; As[lcol + 7][lrow] = a1.w;
        Bs[lcol + 0][lrow] = w0.x; Bs[lcol + 1][lrow] = w0.y;
        Bs[lcol + 2][lrow] = w0.z; Bs[lcol + 3][lrow] = w0.w;
        Bs[lcol + 4][lrow] = w1.x; Bs[lcol + 5][lrow] = w1.y;
        Bs[lcol + 6][lrow] = w1.z; Bs[lcol + 7][lrow] = w1.w;
        __syncthreads();
#pragma unroll
        for (int kk = 0; kk < 16; ++kk) {
            float4 av0 = *(const float4*)&As[kk][ty << 3];
            float4 av1 = *(const float4*)&As[kk][(ty << 3) + 4];
            float4 bv0 = *(const float4*)&Bs[kk][tx << 3];
            float4 bv1 = *(const float4*)&Bs[kk][(tx << 3) + 4];
            float a[8] = {av0.x, av0.y, av0.z, av0.w, av1.x, av1.y, av1.z, av1.w};
            float b[8] = {bv0.x, bv0.y, bv0.z, bv0.w, bv1.x, bv1.y, bv1.z, bv1.w};
#pragma unroll
            for (int i = 0; i < 8; ++i)
#pragma unroll
                for (int j = 0; j < 8; ++j)
                    acc[i][j] = fmaf(a[i], b[j], acc[i][j]);
        }
    }

    float bj[8];
    if (HASBIAS) {
        float4 b0 = *(const float4*)&bias[n0 + (tx << 3)];
        float4 b1 = *(const float4*)&bias[n0 + (tx << 3) + 4];
        bj[0]=b0.x; bj[1]=b0.y; bj[2]=b0.z; bj[3]=b0.w;
        bj[4]=b1.x; bj[5]=b1.y; bj[6]=b1.z; bj[7]=b1.w;
    }
#pragma unroll
    for (int i = 0; i < 8; ++i) {
        const int m = m0 + (ty << 3) + i;
        float v[8];
#pragma unroll
        for (int j = 0; j < 8; ++j) {
            v[j] = acc[i][j];
            if (HASBIAS) v[j] += bj[j];
            if (RELU)    v[j] = fmaxf(v[j], 0.0f);
        }
        float4 s0 = {v[0], v[1], v[2], v[3]};
        float4 s1 = {v[4], v[5], v[6], v[7]};
        *(float4*)&C[(size_t)m * N + n0 + (tx << 3)]     = s0;
        *(float4*)&C[(size_t)m * N + n0 + (tx << 3) + 4] = s1;
    }
}

// ---------------------------------------------------------------------------
// Flash-style tiled attention. One block per (b, h, 64-row q-tile).
// ---------------------------------------------------------------------------
__global__ __launch_bounds__(256) void attn_tile_kernel(
    const float* __restrict__ Qb, int q_rs, int q_hs,
    const float* __restrict__ Kb, int k_rs, int k_hs,
    const float* __restrict__ Vb, int v_rs, int v_hs,
    const float* __restrict__ addmask, int causal,
    float* __restrict__ ctx, int SQ, int SK)
{
    const int qt = blockIdx.x, h = blockIdx.y, b = blockIdx.z;
    const int t  = threadIdx.x;
    const int q0 = qt << 6;

    __shared__ float sQT[64][68];   // Q transposed: [d][q]
    __shared__ float sKP[64][68];   // K transposed [d][k], then P [k][q]
    __shared__ float sV [64][68];   // V natural:   [k][d]

    const int lr = t & 63;
    const int dc = (t >> 6) << 4;

    {
        const float* Qrow = Qb + (size_t)(b * SQ + q0 + lr) * q_rs + h * q_hs + dc;
#pragma unroll
        for (int u = 0; u < 4; ++u) {
            float4 v = *(const float4*)(Qrow + u * 4);
            sQT[dc + u * 4 + 0][lr] = v.x;
            sQT[dc + u * 4 + 1][lr] = v.y;
            sQT[dc + u * 4 + 2][lr] = v.z;
            sQT[dc + u * 4 + 3][lr] = v.w;
        }
    }

    const int tx = t & 15;
    const int ty = t >> 4;

    float M[4], L[4], o[4][4];
#pragma unroll
    for (int i = 0; i < 4; ++i) {
        M[i] = -INFINITY; L[i] = 0.0f;
#pragma unroll
        for (int j = 0; j < 4; ++j) o[i][j] = 0.0f;
    }

    const int nkt = causal ? (qt + 1) : (SK >> 6);

    for (int kt = 0; kt < nkt; ++kt) {
        const int k0 = kt << 6;
        __syncthreads();
        {
            const float* Krow = Kb + (size_t)(b * SK + k0 + lr) * k_rs + h * k_hs + dc;
            const float* Vrow = Vb + (size_t)(b * SK + k0 + lr) * v_rs + h * v_hs + dc;
#pragma unroll
            for (int u = 0; u < 4; ++u) {
                float4 kv = *(const float4*)(Krow + u * 4);
                sKP[dc + u * 4 + 0][lr] = kv.x;
                sKP[dc + u * 4 + 1][lr] = kv.y;
                sKP[dc + u * 4 + 2][lr] = kv.z;
                sKP[dc + u * 4 + 3][lr] = kv.w;
                *(float4*)&sV[lr][dc + u * 4] = *(const float4*)(Vrow + u * 4);
            }
        }
        __syncthreads();

        float s[4][4] = {};
#pragma unroll 16
        for (int d = 0; d < 64; ++d) {
            float4 aq = *(const float4*)&sQT[d][ty << 2];
            float4 bk = *(const float4*)&sKP[d][tx << 2];
            float a[4] = {aq.x, aq.y, aq.z, aq.w};
            float bb[4] = {bk.x, bk.y, bk.z, bk.w};
#pragma unroll
            for (int i = 0; i < 4; ++i)
#pragma unroll
                for (int j = 0; j < 4; ++j)
                    s[i][j] = fmaf(a[i], bb[j], s[i][j]);
        }

#pragma unroll
        for (int j = 0; j < 4; ++j) {
            const int k = k0 + (tx << 2) + j;
            const float m = addmask ? addmask[(size_t)b * SK + k] : 0.0f;
#pragma unroll
            for (int i = 0; i < 4; ++i) {
                float sv = (s[i][j] + m) * INV_SCALE;
                if (causal && k > q0 + (ty << 2) + i) sv = -INFINITY;
                s[i][j] = sv;
            }
        }

        float mx[4];
#pragma unroll
        for (int i = 0; i < 4; ++i)
            mx[i] = fmaxf(fmaxf(s[i][0], s[i][1]), fmaxf(s[i][2], s[i][3]));
#pragma unroll
        for (int off = 1; off < 16; off <<= 1) {
#pragma unroll
            for (int i = 0; i < 4; ++i)
                mx[i] = fmaxf(mx[i], __shfl_xor(mx[i], off, 64));
        }

        float al[4];
#pragma unroll
        for (int i = 0; i < 4; ++i) {
            const float Mn = fmaxf(M[i], mx[i]);
            al[i] = expf(M[i] - Mn);
            M[i]  = Mn;
        }
        float rs[4] = {};
#pragma unroll
        for (int i = 0; i < 4; ++i) {
#pragma unroll
            for (int j = 0; j < 4; ++j) {
                const float p = expf(s[i][j] - M[i]);
                s[i][j] = p;
                rs[i] += p;
            }
        }
#pragma unroll
        for (int off = 1; off < 16; off <<= 1) {
#pragma unroll
            for (int i = 0; i < 4; ++i)
                rs[i] += __shfl_xor(rs[i], off, 64);
        }
#pragma unroll
        for (int i = 0; i < 4; ++i) {
            L[i] = L[i] * al[i] + rs[i];
#pragma unroll
            for (int j = 0; j < 4; ++j) o[i][j] *= al[i];
        }

        __syncthreads();
#pragma unroll
        for (int j = 0; j < 4; ++j)
#pragma unroll
            for (int i = 0; i < 4; ++i)
                sKP[(tx << 2) + j][(ty << 2) + i] = s[i][j];
        __syncthreads();

#pragma unroll 16
        for (int kk = 0; kk < 64; ++kk) {
            float4 pa = *(const float4*)&sKP[kk][ty << 2];
            float4 vb = *(const float4*)&sV[kk][tx << 2];
            float a[4] = {pa.x, pa.y, pa.z, pa.w};
            float bb[4] = {vb.x, vb.y, vb.z, vb.w};
#pragma unroll
            for (int i = 0; i < 4; ++i)
#pragma unroll
                for (int j = 0; j < 4; ++j)
                    o[i][j] = fmaf(a[i], bb[j], o[i][j]);
        }
    }

#pragma unroll
    for (int i = 0; i < 4; ++i) {
        const float inv = 1.0f / L[i];
        float4 w;
        w.x = o[i][0] * inv; w.y = o[i][1] * inv;
        w.z = o[i][2] * inv; w.w = o[i][3] * inv;
        const int q = q0 + (ty << 2) + i;
        *(float4*)&ctx[(size_t)(b * SQ + q) * EMB + h * DK + (tx << 2)] = w;
    }
}

// ---------------------------------------------------------------------------
// x[row,:] = LayerNorm(x[row,:] + delta[row,:]) * g + b   (row length 512)
// ---------------------------------------------------------------------------
__global__ __launch_bounds__(256) void add_ln_kernel(
    float* __restrict__ x, const float* __restrict__ delta,
    const float* __restrict__ g, const float* __restrict__ b)
{
    const int row = blockIdx.x;
    const int t = threadIdx.x;
    __shared__ float red[256];
    const size_t base = (size_t)row * EMB;

    float v0 = x[base + t]       + delta[base + t];
    float v1 = x[base + 256 + t] + delta[base + 256 + t];

    red[t] = v0 + v1; __syncthreads();
    for (int o = 128; o > 0; o >>= 1) {
        if (t < o) red[t] += red[t + o];
        __syncthreads();
    }
    const float mean = red[0] * (1.0f / (float)EMB);
    __syncthreads();

    const float a0 = v0 - mean, a1 = v1 - mean;
    red[t] = a0 * a0 + a1 * a1; __syncthreads();
    for (int o = 128; o > 0; o >>= 1) {
        if (t < o) red[t] += red[t + o];
        __syncthreads();
    }
    const float inv = 1.0f / sqrtf(red[0] * (1.0f / (float)EMB) + 1e-5f);

    x[base + t]       = a0 * inv * g[t]       + b[t];
    x[base + 256 + t] = a1 * inv * g[256 + t] + b[256 + t];
}

// ---------------------------------------------------------------------------
// Row softmax over VOCAB (in place). One block per row, online max/sum.
// ---------------------------------------------------------------------------
__global__ __launch_bounds__(256) void softmax_vocab_kernel(float* __restrict__ X)
{
    const int row = blockIdx.x;
    const int t = threadIdx.x;
    __shared__ float rm[256], rs[256];
    float* x = X + (size_t)row * VOCAB;

    float m = -INFINITY, s = 0.0f;
    for (int k = t; k < VOCAB; k += 256) {
        float v = x[k];
        if (v > m) { s = s * expf(m - v) + 1.0f; m = v; }
        else       { s += expf(v - m); }
    }
    rm[t] = m; rs[t] = s; __syncthreads();
    for (int o = 128; o > 0; o >>= 1) {
        if (t < o) {
            float m1 = rm[t], m2 = rm[t + o];
            float s1 = rs[t], s2 = rs[t + o];
            float MM = fmaxf(m1, m2);
            rs[t] = s1 * expf(m1 - MM) + s2 * expf(m2 - MM);
            rm[t] = MM;
        }
        __syncthreads();
    }
    const float M = rm[0];
    const float inv = 1.0f / rs[0];
    for (int k = t; k < VOCAB; k += 256) x[k] = expf(x[k] - M) * inv;
}

// ---------------------------------------------------------------------------
// Host orchestration
// ---------------------------------------------------------------------------
static inline void launch_gemm(const float* A, const float* W, const float* bias,
                               float* C, int M, int N, int K, bool relu,
                               hipStream_t stream)
{
    if ((M % 128 == 0) && (N % 128 == 0) && N >= 1024) {
        dim3 grid((unsigned)(N / 128), (unsigned)(M / 128));
        if (bias) {
            if (relu) gemm_tn_128<true, true ><<<grid, 256, 0, stream>>>(A, W, bias, C, M, N, K);
            else      gemm_tn_128<true, false><<<grid, 256, 0, stream>>>(A, W, bias, C, M, N, K);
        } else {
            gemm_tn_128<false, false><<<grid, 256, 0, stream>>>(A, W, nullptr, C, M, N, K);
        }
        return;
    }
    dim3 grid((unsigned)(N / 64), (unsigned)(M / 64));
    if (bias) {
        if (relu) gemm_tn<true, true ><<<grid, 256, 0, stream>>>(A, W, bias, C, M, N, K);
        else      gemm_tn<true, false><<<grid, 256, 0, stream>>>(A, W, bias, C, M, N, K);
    } else {
        gemm_tn<false, false><<<grid, 256, 0, stream>>>(A, W, nullptr, C, M, N, K);
    }
}

extern "C" void kernel_launch(void* const* d_in, const int* in_sizes, int n_in,
                              void* d_out, int out_size, void* d_ws, size_t ws_size,
                              hipStream_t stream)
{
    const int*   enc      = (const int*)  d_in[0];
    const int*   dec      = (const int*)  d_in[1];
    const float* enc_mask = (const float*)d_in[2];
    const float* dec_mask = (const float*)d_in[3];
    // d_in[4], d_in[5]: enc_num/dec_num == 6 (compile-time constants)
    const float* emb    = (const float*)d_in[6];
    const float* w_qkv  = (const float*)d_in[7];
    const float* w_lin  = (const float*)d_in[8];
    const float* b_lin  = (const float*)d_in[9];
    const float* w_ff1  = (const float*)d_in[10];
    const float* b_ff1  = (const float*)d_in[11];
    const float* w_ff2  = (const float*)d_in[12];
    const float* b_ff2  = (const float*)d_in[13];
    const float* w_out  = (const float*)d_in[14];
    const float* b_out  = (const float*)d_in[15];
    const float* ln_e1g = (const float*)d_in[16];
    const float* ln_e1b = (const float*)d_in[17];
    const float* ln_e2g = (const float*)d_in[18];
    const float* ln_e2b = (const float*)d_in[19];
    const float* ln_d1g = (const float*)d_in[20];
    const float* ln_d1b = (const float*)d_in[21];
    const float* ln_d2g = (const float*)d_in[22];
    const float* ln_d2b = (const float*)d_in[23];
    const float* ln_d3g = (const float*)d_in[24];
    const float* ln_d3b = (const float*)d_in[25];

    float* out = (float*)d_out;

    const size_t sz_x   = (size_t)TOK * EMB * sizeof(float);     // 8 MB
    const size_t sz_qkv = (size_t)TOK * 3 * EMB * sizeof(float); // 25 MB
    const size_t sz_ff  = (size_t)TOK * FF * sizeof(float);      // 33.5 MB
    const size_t sz_wbf = (size_t)VOCAB * EMB * sizeof(unsigned short); // 32.8 MB
    const size_t sz_abf = (size_t)TOK * EMB * sizeof(unsigned short);   // 4.2 MB
    const size_t need      = 2 * sz_x + 2 * sz_qkv + 2 * sz_x + sz_ff;
    const size_t need_mfma = need + sz_wbf + sz_abf;

    char* wsp = (char*)d_ws;
    float* x_d_buf = (float*)wsp; wsp += sz_x;
    float *x_e, *qkv, *ekv, *ctxb, *tmpb, *ffb;
    unsigned short *w_bf = nullptr, *a_bf = nullptr;
    bool use_mfma = false;
    if (ws_size >= need) {
        x_e  = (float*)wsp; wsp += sz_x;
        qkv  = (float*)wsp; wsp += sz_qkv;
        ekv  = (float*)wsp; wsp += sz_qkv;
        ctxb = (float*)wsp; wsp += sz_x;
        tmpb = (float*)wsp; wsp += sz_x;
        ffb  = (float*)wsp; wsp += sz_ff;
        if (ws_size >= need_mfma) {
            w_bf = (unsigned short*)wsp; wsp += sz_wbf;
            a_bf = (unsigned short*)wsp;
            use_mfma = true;
        }
    } else {
        char* op = (char*)d_out;   // scratch inside d_out; dead before final GEMM
        x_e  = (float*)op; op += sz_x;
        qkv  = (float*)op; op += sz_qkv;
        ekv  = (float*)op; op += sz_qkv;
        ctxb = (float*)op; op += sz_x;
        tmpb = (float*)op; op += sz_x;
        ffb  = (float*)op;
    }

    const dim3 attn_grid(SEQ / 64, HEADS, BATCH);   // (8, 8, 8)
    const int  embed_blocks = (TOK * EMB) / 256;

    embed_pe_kernel<<<embed_blocks, 256, 0, stream>>>(enc, emb, x_e);
    embed_pe_kernel<<<embed_blocks, 256, 0, stream>>>(dec, emb, x_d_buf);

    // ---------------- Encoder (6 layers) ----------------
    for (int l = 0; l < 6; ++l) {
        launch_gemm(x_e, w_qkv, nullptr, qkv, TOK, 3 * EMB, EMB, false, stream);
        attn_tile_kernel<<<attn_grid, 256, 0, stream>>>(
            qkv,        3 * EMB, 3 * DK,
            qkv + DK,   3 * EMB, 3 * DK,
            qkv + 2*DK, 3 * EMB, 3 * DK,
            enc_mask, 0, ctxb, SEQ, SEQ);
        launch_gemm(ctxb, w_lin, b_lin, tmpb, TOK, EMB, EMB, false, stream);
        add_ln_kernel<<<TOK, 256, 0, stream>>>(x_e, tmpb, ln_e1g, ln_e1b);
        launch_gemm(x_e, w_ff1, b_ff1, ffb, TOK, FF, EMB, true, stream);
        launch_gemm(ffb, w_ff2, b_ff2, tmpb, TOK, EMB, FF, false, stream);
        add_ln_kernel<<<TOK, 256, 0, stream>>>(x_e, tmpb, ln_e2g, ln_e2b);
    }

    launch_gemm(x_e, w_qkv, nullptr, ekv, TOK, 3 * EMB, EMB, false, stream);

    // ---------------- Decoder (6 layers) ----------------
    for (int l = 0; l < 6; ++l) {
        launch_gemm(x_d_buf, w_qkv, nullptr, qkv, TOK, 3 * EMB, EMB, false, stream);
        attn_tile_kernel<<<attn_grid, 256, 0, stream>>>(
            qkv,        3 * EMB, 3 * DK,
            qkv + DK,   3 * EMB, 3 * DK,
            qkv + 2*DK, 3 * EMB, 3 * DK,
            dec_mask, 1, ctxb, SEQ, SEQ);
        launch_gemm(ctxb, w_lin, b_lin, tmpb, TOK, EMB, EMB, false, stream);
        add_ln_kernel<<<TOK, 256, 0, stream>>>(x_d_buf, tmpb, ln_d1g, ln_d1b);

        launch_gemm(x_d_buf, w_qkv, nullptr, qkv, TOK, EMB, EMB, false, stream);
        attn_tile_kernel<<<attn_grid, 256, 0, stream>>>(
            qkv,          EMB,     DK,
            ekv + DK,     3 * EMB, 3 * DK,
            ekv + 2*DK,   3 * EMB, 3 * DK,
            enc_mask, 0, ctxb, SEQ, SEQ);
        launch_gemm(ctxb, w_lin, b_lin, tmpb, TOK, EMB, EMB, false, stream);
        add_ln_kernel<<<TOK, 256, 0, stream>>>(x_d_buf, tmpb, ln_d2g, ln_d2b);

        launch_gemm(x_d_buf, w_ff1, b_ff1, ffb, TOK, FF, EMB, true, stream);
        launch_gemm(ffb, w_ff2, b_ff2, tmpb, TOK, EMB, FF, false, stream);
        add_ln_kernel<<<TOK, 256, 0, stream>>>(x_d_buf, tmpb, ln_d3g, ln_d3b);
    }

    // ---------------- Output projection + softmax ----------------
    if (use_mfma) {
        cast_f32_to_bf16<<<(VOCAB * EMB / 8) / 256, 256, 0, stream>>>(
            w_out, w_bf, VOCAB * EMB / 8);
        cast_f32_to_bf16<<<(TOK * EMB / 8) / 256, 256, 0, stream>>>(
            x_d_buf, a_bf, TOK * EMB / 8);
        dim3 vgrid(VOCAB / 128, TOK / 128);
        gemm_bf16_mfma<<<vgrid, 256, 0, stream>>>(a_bf, w_bf, b_out, out,
                                                  TOK, VOCAB, EMB);
    } else {
        launch_gemm(x_d_buf, w_out, b_out, out, TOK, VOCAB, EMB, false, stream);
    }
    softmax_vocab_kernel<<<TOK, 256, 0, stream>>>(out);
}

// Round 4
// 5113.279 us; speedup vs baseline: 7.7964x; 1.6252x over previous
//
#include <hip/hip_runtime.h>
#include <cmath>

// Problem constants
#define BATCH 8
#define SEQ   512
#define EMB   512
#define HEADS 8
#define DK    64
#define FF    2048
#define VOCAB 32000
#define TOK   (BATCH * SEQ)   // 4096 rows
#define INV_SCALE 0.125f      // 1/sqrt(64)

typedef __attribute__((ext_vector_type(8))) short bf16x8;
typedef __attribute__((ext_vector_type(4))) float f32x4;

__device__ __forceinline__ unsigned short f2bf(float f) {
    unsigned int u = __float_as_uint(f);
    return (unsigned short)((u + 0x7FFFu + ((u >> 16) & 1u)) >> 16);
}

// ---------------------------------------------------------------------------
// Embedding lookup + positional encoding; writes f32 and (optional) bf16 copy
// ---------------------------------------------------------------------------
__global__ __launch_bounds__(256) void embed_pe_kernel(
    const int* __restrict__ tok, const float* __restrict__ table,
    float* __restrict__ out, unsigned short* __restrict__ outbf)
{
    int idx = blockIdx.x * 256 + threadIdx.x;      // < TOK*EMB = 2M
    int d   = idx & (EMB - 1);
    int row = idx >> 9;                            // EMB = 512 = 2^9
    int s   = row & (SEQ - 1);                     // SEQ = 512
    float p   = powf(10000.0f, (2.0f * (float)d) * (1.0f / (float)EMB));
    float ang = (float)s / p;
    float pe  = ((d & 1) == 0) ? sinf(ang) : cosf(ang);
    float v   = table[(size_t)tok[row] * EMB + d] + pe;
    out[idx] = v;
    if (outbf) outbf[idx] = f2bf(v);
}

// ---------------------------------------------------------------------------
// f32 -> bf16 cast (RNE), 8 elements per thread. n8 = count/8.
// ---------------------------------------------------------------------------
__global__ __launch_bounds__(256) void cast_f32_to_bf16(
    const float* __restrict__ in, unsigned short* __restrict__ out, int n8)
{
    int i = blockIdx.x * 256 + threadIdx.x;
    if (i >= n8) return;
    const float4* p = (const float4*)(in + (size_t)i * 8);
    float4 f0 = p[0], f1 = p[1];
    float v[8] = {f0.x, f0.y, f0.z, f0.w, f1.x, f1.y, f1.z, f1.w};
    union { unsigned short u[8]; int4 v4; } r;
#pragma unroll
    for (int j = 0; j < 8; ++j) r.u[j] = f2bf(v[j]);
    *(int4*)(out + (size_t)i * 8) = r.v4;
}

// ---------------------------------------------------------------------------
// bf16 MFMA GEMM: C[M,N] = A[M,K] @ B[N,K]^T (+bias) (opt ReLU, f32/bf16 out)
// Tile 128 x (NF*32), BK=64, 256 threads = 4 waves 2x2, wave = 64 x (NF*16).
// mfma_f32_16x16x32_bf16; LDS rows padded to 72 bf16 (2-way max on b128).
// ---------------------------------------------------------------------------
#define MF_LDA 72
template<int NF, bool HASBIAS, bool RELU, bool BF16OUT>
__global__ __launch_bounds__(256) void gemm_bf16_mfma(
    const unsigned short* __restrict__ A,   // [M][K] bf16
    const unsigned short* __restrict__ B,   // [N][K] bf16
    const float* __restrict__ bias,         // [N] or null
    void* __restrict__ Cout, int M, int N, int K)
{
    constexpr int BN = NF * 32;
    __shared__ unsigned short As[128 * MF_LDA];
    __shared__ unsigned short Bs[BN * MF_LDA];
    const int tid  = threadIdx.x;
    const int m0   = blockIdx.y << 7;
    const int n0   = blockIdx.x * BN;
    const int wave = tid >> 6;
    const int lane = tid & 63;
    const int wm   = (wave >> 1) << 6;       // wave row offset
    const int wn   = (wave & 1) * (NF * 16); // wave col offset
    const int l15  = lane & 15;
    const int lg   = lane >> 4;              // 0..3

    f32x4 acc[4][NF] = {};

    constexpr int CH_A = 128 * 8;            // 16B chunks for A tile
    constexpr int CH_B = BN * 8;
    constexpr int NIT  = (CH_A + CH_B) / 256;

    for (int k0 = 0; k0 < K; k0 += 64) {
        __syncthreads();   // previous tile's fragment reads done
#pragma unroll
        for (int it = 0; it < NIT; ++it) {
            const int c = it * 256 + tid;
            if (c < CH_A) {
                const int row = c >> 3, kc = c & 7;
                *(int4*)&As[row * MF_LDA + kc * 8] =
                    *(const int4*)&A[(size_t)(m0 + row) * K + k0 + kc * 8];
            } else {
                const int cc = c - CH_A, row = cc >> 3, kc = cc & 7;
                *(int4*)&Bs[row * MF_LDA + kc * 8] =
                    *(const int4*)&B[(size_t)(n0 + row) * K + k0 + kc * 8];
            }
        }
        __syncthreads();

#pragma unroll
        for (int ks = 0; ks < 2; ++ks) {
            const int kch = ks * 4 + lg;
            bf16x8 af[4], bfr[NF];
#pragma unroll
            for (int mi = 0; mi < 4; ++mi)
                af[mi] = *(const bf16x8*)&As[(wm + mi * 16 + l15) * MF_LDA + kch * 8];
#pragma unroll
            for (int ni = 0; ni < NF; ++ni)
                bfr[ni] = *(const bf16x8*)&Bs[(wn + ni * 16 + l15) * MF_LDA + kch * 8];
#pragma unroll
            for (int mi = 0; mi < 4; ++mi)
#pragma unroll
                for (int ni = 0; ni < NF; ++ni)
                    acc[mi][ni] = __builtin_amdgcn_mfma_f32_16x16x32_bf16(
                        af[mi], bfr[ni], acc[mi][ni], 0, 0, 0);
        }
    }

    // C/D layout: col = lane&15 (N), row = (lane>>4)*4 + r (M)
#pragma unroll
    for (int mi = 0; mi < 4; ++mi) {
        const int mb = m0 + wm + mi * 16 + lg * 4;
#pragma unroll
        for (int ni = 0; ni < NF; ++ni) {
            const int n = n0 + wn + ni * 16 + l15;
            const float bv = HASBIAS ? bias[n] : 0.0f;
#pragma unroll
            for (int r = 0; r < 4; ++r) {
                float v = acc[mi][ni][r] + bv;
                if (RELU) v = fmaxf(v, 0.0f);
                if (BF16OUT)
                    ((unsigned short*)Cout)[(size_t)(mb + r) * N + n] = f2bf(v);
                else
                    ((float*)Cout)[(size_t)(mb + r) * N + n] = v;
            }
        }
    }
}

template<int NF, bool HB, bool RL, bool BO>
static inline void launch_mfma(const unsigned short* A, const unsigned short* B,
                               const float* bias, void* C, int M, int N, int K,
                               hipStream_t s)
{
    dim3 grid((unsigned)(N / (NF * 32)), (unsigned)(M / 128));
    gemm_bf16_mfma<NF, HB, RL, BO><<<grid, 256, 0, s>>>(A, B, bias, C, M, N, K);
}

// ---------------------------------------------------------------------------
// Legacy f32 GEMMs (fallback path only)
// ---------------------------------------------------------------------------
template<bool HASBIAS, bool RELU>
__global__ __launch_bounds__(256) void gemm_tn(
    const float* __restrict__ A, const float* __restrict__ W,
    const float* __restrict__ bias, float* __restrict__ C,
    int M, int N, int K)
{
    __shared__ float As[16][64];
    __shared__ float Bs[16][64];
    const int tid = threadIdx.x;
    const int tx  = tid & 15;
    const int ty  = tid >> 4;
    const int m0  = blockIdx.y << 6;
    const int n0  = blockIdx.x << 6;
    const int lrow = tid >> 2;
    const int lcol = (tid & 3) << 2;

    const float* Aload = A + (size_t)(m0 + lrow) * K + lcol;
    const float* Wload = W + (size_t)(n0 + lrow) * K + lcol;

    float acc[4][4] = {};

    for (int k0 = 0; k0 < K; k0 += 16) {
        float4 a4 = *(const float4*)(Aload + k0);
        float4 w4 = *(const float4*)(Wload + k0);
        As[lcol + 0][lrow] = a4.x; As[lcol + 1][lrow] = a4.y;
        As[lcol + 2][lrow] = a4.z; As[lcol + 3][lrow] = a4.w;
        Bs[lcol + 0][lrow] = w4.x; Bs[lcol + 1][lrow] = w4.y;
        Bs[lcol + 2][lrow] = w4.z; Bs[lcol + 3][lrow] = w4.w;
        __syncthreads();
#pragma unroll
        for (int kk = 0; kk < 16; ++kk) {
            float4 av = *(const float4*)&As[kk][ty << 2];
            float4 bv = *(const float4*)&Bs[kk][tx << 2];
            float a[4] = {av.x, av.y, av.z, av.w};
            float b[4] = {bv.x, bv.y, bv.z, bv.w};
#pragma unroll
            for (int i = 0; i < 4; ++i)
#pragma unroll
                for (int j = 0; j < 4; ++j)
                    acc[i][j] = fmaf(a[i], b[j], acc[i][j]);
        }
        __syncthreads();
    }

#pragma unroll
    for (int i = 0; i < 4; ++i) {
        const int m = m0 + (ty << 2) + i;
#pragma unroll
        for (int j = 0; j < 4; ++j) {
            const int n = n0 + (tx << 2) + j;
            float v = acc[i][j];
            if (HASBIAS) v += bias[n];
            if (RELU)    v = fmaxf(v, 0.0f);
            C[(size_t)m * N + n] = v;
        }
    }
}

template<bool HASBIAS, bool RELU>
__global__ __launch_bounds__(256) void gemm_tn_128(
    const float* __restrict__ A, const float* __restrict__ W,
    const float* __restrict__ bias, float* __restrict__ C,
    int M, int N, int K)
{
    __shared__ float As[16][132];
    __shared__ float Bs[16][132];
    const int tid = threadIdx.x;
    const int tx  = tid & 15;
    const int ty  = tid >> 4;
    const int m0  = blockIdx.y << 7;
    const int n0  = blockIdx.x << 7;
    const int lrow = tid >> 1;
    const int lcol = (tid & 1) << 3;

    const float* Aload = A + (size_t)(m0 + lrow) * K + lcol;
    const float* Wload = W + (size_t)(n0 + lrow) * K + lcol;

    float acc[8][8] = {};

    for (int k0 = 0; k0 < K; k0 += 16) {
        float4 a0 = *(const float4*)(Aload + k0);
        float4 a1 = *(const float4*)(Aload + k0 + 4);
        float4 w0 = *(const float4*)(Wload + k0);
        float4 w1 = *(const float4*)(Wload + k0 + 4);
        __syncthreads();
        As[lcol + 0][lrow] = a0.x; As[lcol + 1][lrow] = a0.y;
        As[lcol + 2][lrow] = a0.z; As[lcol + 3][lrow] = a0.w;
        As[lcol + 4][lrow] = a1.x; As[lcol + 5][lrow] = a1.y;
        As[lcol + 6][lrow] = a1.z; As[lcol + 7][lrow] = a1.w;
        Bs[lcol + 0][lrow] = w0.x; Bs[lcol + 1][lrow] = w0.y;
        Bs[lcol + 2][lrow] = w0.z; Bs[lcol + 3][lrow] = w0.w;
        Bs[lcol + 4][lrow] = w1.x; Bs[lcol + 5][lrow] = w1.y;
        Bs[lcol + 6][lrow] = w1.z; Bs[lcol + 7][lrow] = w1.w;
        __syncthreads();
#pragma unroll
        for (int kk = 0; kk < 16; ++kk) {
            float4 av0 = *(const float4*)&As[kk][ty << 3];
            float4 av1 = *(const float4*)&As[kk][(ty << 3) + 4];
            float4 bv0 = *(const float4*)&Bs[kk][tx << 3];
            float4 bv1 = *(const float4*)&Bs[kk][(tx << 3) + 4];
            float a[8] = {av0.x, av0.y, av0.z, av0.w, av1.x, av1.y, av1.z, av1.w};
            float b[8] = {bv0.x, bv0.y, bv0.z, bv0.w, bv1.x, bv1.y, bv1.z, bv1.w};
#pragma unroll
            for (int i = 0; i < 8; ++i)
#pragma unroll
                for (int j = 0; j < 8; ++j)
                    acc[i][j] = fmaf(a[i], b[j], acc[i][j]);
        }
    }

    float bj[8];
    if (HASBIAS) {
        float4 b0 = *(const float4*)&bias[n0 + (tx << 3)];
        float4 b1 = *(const float4*)&bias[n0 + (tx << 3) + 4];
        bj[0]=b0.x; bj[1]=b0.y; bj[2]=b0.z; bj[3]=b0.w;
        bj[4]=b1.x; bj[5]=b1.y; bj[6]=b1.z; bj[7]=b1.w;
    }
#pragma unroll
    for (int i = 0; i < 8; ++i) {
        const int m = m0 + (ty << 3) + i;
        float v[8];
#pragma unroll
        for (int j = 0; j < 8; ++j) {
            v[j] = acc[i][j];
            if (HASBIAS) v[j] += bj[j];
            if (RELU)    v[j] = fmaxf(v[j], 0.0f);
        }
        float4 s0 = {v[0], v[1], v[2], v[3]};
        float4 s1 = {v[4], v[5], v[6], v[7]};
        *(float4*)&C[(size_t)m * N + n0 + (tx << 3)]     = s0;
        *(float4*)&C[(size_t)m * N + n0 + (tx << 3) + 4] = s1;
    }
}

static inline void launch_gemm_f32(const float* A, const float* W, const float* bias,
                                   float* C, int M, int N, int K, bool relu,
                                   hipStream_t stream)
{
    if ((M % 128 == 0) && (N % 128 == 0) && N >= 1024) {
        dim3 grid((unsigned)(N / 128), (unsigned)(M / 128));
        if (bias) {
            if (relu) gemm_tn_128<true, true ><<<grid, 256, 0, stream>>>(A, W, bias, C, M, N, K);
            else      gemm_tn_128<true, false><<<grid, 256, 0, stream>>>(A, W, bias, C, M, N, K);
        } else {
            gemm_tn_128<false, false><<<grid, 256, 0, stream>>>(A, W, nullptr, C, M, N, K);
        }
        return;
    }
    dim3 grid((unsigned)(N / 64), (unsigned)(M / 64));
    if (bias) {
        if (relu) gemm_tn<true, true ><<<grid, 256, 0, stream>>>(A, W, bias, C, M, N, K);
        else      gemm_tn<true, false><<<grid, 256, 0, stream>>>(A, W, bias, C, M, N, K);
    } else {
        gemm_tn<false, false><<<grid, 256, 0, stream>>>(A, W, nullptr, C, M, N, K);
    }
}

// ---------------------------------------------------------------------------
// Flash-style tiled attention. One block per (b, h, 64-row q-tile).
// ctx written as bf16 (CTXBF) or f32.
// ---------------------------------------------------------------------------
template<bool CTXBF>
__global__ __launch_bounds__(256) void attn_tile_kernel(
    const float* __restrict__ Qb, int q_rs, int q_hs,
    const float* __restrict__ Kb, int k_rs, int k_hs,
    const float* __restrict__ Vb, int v_rs, int v_hs,
    const float* __restrict__ addmask, int causal,
    void* __restrict__ ctx, int SQ, int SK)
{
    const int qt = blockIdx.x, h = blockIdx.y, b = blockIdx.z;
    const int t  = threadIdx.x;
    const int q0 = qt << 6;

    __shared__ float sQT[64][68];   // Q transposed: [d][q]
    __shared__ float sKP[64][68];   // K transposed [d][k], then P [k][q]
    __shared__ float sV [64][68];   // V natural:   [k][d]

    const int lr = t & 63;
    const int dc = (t >> 6) << 4;

    {
        const float* Qrow = Qb + (size_t)(b * SQ + q0 + lr) * q_rs + h * q_hs + dc;
#pragma unroll
        for (int u = 0; u < 4; ++u) {
            float4 v = *(const float4*)(Qrow + u * 4);
            sQT[dc + u * 4 + 0][lr] = v.x;
            sQT[dc + u * 4 + 1][lr] = v.y;
            sQT[dc + u * 4 + 2][lr] = v.z;
            sQT[dc + u * 4 + 3][lr] = v.w;
        }
    }

    const int tx = t & 15;
    const int ty = t >> 4;

    float M[4], L[4], o[4][4];
#pragma unroll
    for (int i = 0; i < 4; ++i) {
        M[i] = -INFINITY; L[i] = 0.0f;
#pragma unroll
        for (int j = 0; j < 4; ++j) o[i][j] = 0.0f;
    }

    const int nkt = causal ? (qt + 1) : (SK >> 6);

    for (int kt = 0; kt < nkt; ++kt) {
        const int k0 = kt << 6;
        __syncthreads();
        {
            const float* Krow = Kb + (size_t)(b * SK + k0 + lr) * k_rs + h * k_hs + dc;
            const float* Vrow = Vb + (size_t)(b * SK + k0 + lr) * v_rs + h * v_hs + dc;
#pragma unroll
            for (int u = 0; u < 4; ++u) {
                float4 kv = *(const float4*)(Krow + u * 4);
                sKP[dc + u * 4 + 0][lr] = kv.x;
                sKP[dc + u * 4 + 1][lr] = kv.y;
                sKP[dc + u * 4 + 2][lr] = kv.z;
                sKP[dc + u * 4 + 3][lr] = kv.w;
                *(float4*)&sV[lr][dc + u * 4] = *(const float4*)(Vrow + u * 4);
            }
        }
        __syncthreads();

        float s[4][4] = {};
#pragma unroll 16
        for (int d = 0; d < 64; ++d) {
            float4 aq = *(const float4*)&sQT[d][ty << 2];
            float4 bk = *(const float4*)&sKP[d][tx << 2];
            float a[4] = {aq.x, aq.y, aq.z, aq.w};
            float bb[4] = {bk.x, bk.y, bk.z, bk.w};
#pragma unroll
            for (int i = 0; i < 4; ++i)
#pragma unroll
                for (int j = 0; j < 4; ++j)
                    s[i][j] = fmaf(a[i], bb[j], s[i][j]);
        }

#pragma unroll
        for (int j = 0; j < 4; ++j) {
            const int k = k0 + (tx << 2) + j;
            const float m = addmask ? addmask[(size_t)b * SK + k] : 0.0f;
#pragma unroll
            for (int i = 0; i < 4; ++i) {
                float sv = (s[i][j] + m) * INV_SCALE;
                if (causal && k > q0 + (ty << 2) + i) sv = -INFINITY;
                s[i][j] = sv;
            }
        }

        float mx[4];
#pragma unroll
        for (int i = 0; i < 4; ++i)
            mx[i] = fmaxf(fmaxf(s[i][0], s[i][1]), fmaxf(s[i][2], s[i][3]));
#pragma unroll
        for (int off = 1; off < 16; off <<= 1) {
#pragma unroll
            for (int i = 0; i < 4; ++i)
                mx[i] = fmaxf(mx[i], __shfl_xor(mx[i], off, 64));
        }

        float al[4];
#pragma unroll
        for (int i = 0; i < 4; ++i) {
            const float Mn = fmaxf(M[i], mx[i]);
            al[i] = expf(M[i] - Mn);
            M[i]  = Mn;
        }
        float rs[4] = {};
#pragma unroll
        for (int i = 0; i < 4; ++i) {
#pragma unroll
            for (int j = 0; j < 4; ++j) {
                const float p = expf(s[i][j] - M[i]);
                s[i][j] = p;
                rs[i] += p;
            }
        }
#pragma unroll
        for (int off = 1; off < 16; off <<= 1) {
#pragma unroll
            for (int i = 0; i < 4; ++i)
                rs[i] += __shfl_xor(rs[i], off, 64);
        }
#pragma unroll
        for (int i = 0; i < 4; ++i) {
            L[i] = L[i] * al[i] + rs[i];
#pragma unroll
            for (int j = 0; j < 4; ++j) o[i][j] *= al[i];
        }

        __syncthreads();
#pragma unroll
        for (int j = 0; j < 4; ++j)
#pragma unroll
            for (int i = 0; i < 4; ++i)
                sKP[(tx << 2) + j][(ty << 2) + i] = s[i][j];
        __syncthreads();

#pragma unroll 16
        for (int kk = 0; kk < 64; ++kk) {
            float4 pa = *(const float4*)&sKP[kk][ty << 2];
            float4 vb = *(const float4*)&sV[kk][tx << 2];
            float a[4] = {pa.x, pa.y, pa.z, pa.w};
            float bb[4] = {vb.x, vb.y, vb.z, vb.w};
#pragma unroll
            for (int i = 0; i < 4; ++i)
#pragma unroll
                for (int j = 0; j < 4; ++j)
                    o[i][j] = fmaf(a[i], bb[j], o[i][j]);
        }
    }

#pragma unroll
    for (int i = 0; i < 4; ++i) {
        const float inv = 1.0f / L[i];
        const int q = q0 + (ty << 2) + i;
        const size_t base = (size_t)(b * SQ + q) * EMB + h * DK + (tx << 2);
        if (CTXBF) {
            union { unsigned short u[4]; uint2 v; } r;
            r.u[0] = f2bf(o[i][0] * inv); r.u[1] = f2bf(o[i][1] * inv);
            r.u[2] = f2bf(o[i][2] * inv); r.u[3] = f2bf(o[i][3] * inv);
            *(uint2*)&((unsigned short*)ctx)[base] = r.v;
        } else {
            float4 w;
            w.x = o[i][0] * inv; w.y = o[i][1] * inv;
            w.z = o[i][2] * inv; w.w = o[i][3] * inv;
            *(float4*)&((float*)ctx)[base] = w;
        }
    }
}

// ---------------------------------------------------------------------------
// x = LayerNorm(x + delta) * g + b ; optionally writes bf16 copy of result
// ---------------------------------------------------------------------------
__global__ __launch_bounds__(256) void add_ln_kernel(
    float* __restrict__ x, const float* __restrict__ delta,
    const float* __restrict__ g, const float* __restrict__ b,
    unsigned short* __restrict__ xbf)
{
    const int row = blockIdx.x;
    const int t = threadIdx.x;
    __shared__ float red[256];
    const size_t base = (size_t)row * EMB;

    float v0 = x[base + t]       + delta[base + t];
    float v1 = x[base + 256 + t] + delta[base + 256 + t];

    red[t] = v0 + v1; __syncthreads();
    for (int o = 128; o > 0; o >>= 1) {
        if (t < o) red[t] += red[t + o];
        __syncthreads();
    }
    const float mean = red[0] * (1.0f / (float)EMB);
    __syncthreads();

    const float a0 = v0 - mean, a1 = v1 - mean;
    red[t] = a0 * a0 + a1 * a1; __syncthreads();
    for (int o = 128; o > 0; o >>= 1) {
        if (t < o) red[t] += red[t + o];
        __syncthreads();
    }
    const float inv = 1.0f / sqrtf(red[0] * (1.0f / (float)EMB) + 1e-5f);

    const float r0 = a0 * inv * g[t]       + b[t];
    const float r1 = a1 * inv * g[256 + t] + b[256 + t];
    x[base + t]       = r0;
    x[base + 256 + t] = r1;
    if (xbf) {
        xbf[base + t]       = f2bf(r0);
        xbf[base + 256 + t] = f2bf(r1);
    }
}

// ---------------------------------------------------------------------------
// Row softmax over VOCAB (in place), float4-vectorized. One block per row.
// ---------------------------------------------------------------------------
__global__ __launch_bounds__(256) void softmax_vocab_kernel(float* __restrict__ X)
{
    const int row = blockIdx.x;
    const int t = threadIdx.x;
    __shared__ float rm[256], rs[256];
    float4* x4 = (float4*)(X + (size_t)row * VOCAB);
    const int N4 = VOCAB / 4;   // 8000

    float m = -INFINITY, s = 0.0f;
    for (int c = t; c < N4; c += 256) {
        float4 v = x4[c];
        float lm = fmaxf(fmaxf(v.x, v.y), fmaxf(v.z, v.w));
        if (lm > m) { s *= expf(m - lm); m = lm; }
        s += expf(v.x - m) + expf(v.y - m) + expf(v.z - m) + expf(v.w - m);
    }
    rm[t] = m; rs[t] = s; __syncthreads();
    for (int o = 128; o > 0; o >>= 1) {
        if (t < o) {
            float m1 = rm[t], m2 = rm[t + o];
            float s1 = rs[t], s2 = rs[t + o];
            float MM = fmaxf(m1, m2);
            rs[t] = s1 * expf(m1 - MM) + s2 * expf(m2 - MM);
            rm[t] = MM;
        }
        __syncthreads();
    }
    const float M = rm[0];
    const float inv = 1.0f / rs[0];
    for (int c = t; c < N4; c += 256) {
        float4 v = x4[c];
        v.x = expf(v.x - M) * inv; v.y = expf(v.y - M) * inv;
        v.z = expf(v.z - M) * inv; v.w = expf(v.w - M) * inv;
        x4[c] = v;
    }
}

// ---------------------------------------------------------------------------
// Host orchestration
// ---------------------------------------------------------------------------
extern "C" void kernel_launch(void* const* d_in, const int* in_sizes, int n_in,
                              void* d_out, int out_size, void* d_ws, size_t ws_size,
                              hipStream_t stream)
{
    const int*   enc      = (const int*)  d_in[0];
    const int*   dec      = (const int*)  d_in[1];
    const float* enc_mask = (const float*)d_in[2];
    const float* dec_mask = (const float*)d_in[3];
    const float* emb    = (const float*)d_in[6];
    const float* w_qkv  = (const float*)d_in[7];
    const float* w_lin  = (const float*)d_in[8];
    const float* b_lin  = (const float*)d_in[9];
    const float* w_ff1  = (const float*)d_in[10];
    const float* b_ff1  = (const float*)d_in[11];
    const float* w_ff2  = (const float*)d_in[12];
    const float* b_ff2  = (const float*)d_in[13];
    const float* w_out  = (const float*)d_in[14];
    const float* b_out  = (const float*)d_in[15];
    const float* ln_e1g = (const float*)d_in[16];
    const float* ln_e1b = (const float*)d_in[17];
    const float* ln_e2g = (const float*)d_in[18];
    const float* ln_e2b = (const float*)d_in[19];
    const float* ln_d1g = (const float*)d_in[20];
    const float* ln_d1b = (const float*)d_in[21];
    const float* ln_d2g = (const float*)d_in[22];
    const float* ln_d2b = (const float*)d_in[23];
    const float* ln_d3g = (const float*)d_in[24];
    const float* ln_d3b = (const float*)d_in[25];

    float* out = (float*)d_out;

    const size_t sz_xf   = (size_t)TOK * EMB * sizeof(float);          // 8 MB
    const size_t sz_xbf  = (size_t)TOK * EMB * 2;                      // 4 MB
    const size_t sz_qkv  = (size_t)TOK * 3 * EMB * sizeof(float);      // 25 MB
    const size_t sz_tmp  = sz_xf;
    const size_t sz_ffbf = (size_t)TOK * FF * 2;                       // 16.8 MB
    const size_t sz_wqkv = (size_t)3 * EMB * EMB * 2;
    const size_t sz_wlin = (size_t)EMB * EMB * 2;
    const size_t sz_wff1 = (size_t)FF * EMB * 2;
    const size_t sz_wff2 = (size_t)EMB * FF * 2;
    const size_t sz_wout = (size_t)VOCAB * EMB * 2;                    // 32.8 MB
    const size_t need_bf = 2 * (sz_xf + sz_xbf) + 2 * sz_qkv + sz_xbf + sz_tmp +
                           sz_ffbf + sz_wqkv + sz_wlin + sz_wff1 + sz_wff2 + sz_wout;

    const dim3 attn_grid(SEQ / 64, HEADS, BATCH);   // (8, 8, 8)
    const int  embed_blocks = (TOK * EMB) / 256;

    if (ws_size >= need_bf) {
        // ---------------- bf16-MFMA main path ----------------
        char* p = (char*)d_ws;
        float* x_e            = (float*)p;          p += sz_xf;
        float* x_d            = (float*)p;          p += sz_xf;
        unsigned short* x_e_bf = (unsigned short*)p; p += sz_xbf;
        unsigned short* x_d_bf = (unsigned short*)p; p += sz_xbf;
        float* qkv            = (float*)p;          p += sz_qkv;
        float* ekv            = (float*)p;          p += sz_qkv;
        unsigned short* ctxbf = (unsigned short*)p; p += sz_xbf;
        float* tmpb           = (float*)p;          p += sz_tmp;
        unsigned short* ffbf  = (unsigned short*)p; p += sz_ffbf;
        unsigned short* wqkvb = (unsigned short*)p; p += sz_wqkv;
        unsigned short* wlinb = (unsigned short*)p; p += sz_wlin;
        unsigned short* wff1b = (unsigned short*)p; p += sz_wff1;
        unsigned short* wff2b = (unsigned short*)p; p += sz_wff2;
        unsigned short* woutb = (unsigned short*)p;

        // weight casts (once per launch)
        cast_f32_to_bf16<<<(3*EMB*EMB/8)/256, 256, 0, stream>>>(w_qkv, wqkvb, 3*EMB*EMB/8);
        cast_f32_to_bf16<<<(EMB*EMB/8)/256,   256, 0, stream>>>(w_lin, wlinb, EMB*EMB/8);
        cast_f32_to_bf16<<<(FF*EMB/8)/256,    256, 0, stream>>>(w_ff1, wff1b, FF*EMB/8);
        cast_f32_to_bf16<<<(EMB*FF/8)/256,    256, 0, stream>>>(w_ff2, wff2b, EMB*FF/8);
        cast_f32_to_bf16<<<(VOCAB*EMB/8)/256, 256, 0, stream>>>(w_out, woutb, VOCAB*EMB/8);

        embed_pe_kernel<<<embed_blocks, 256, 0, stream>>>(enc, emb, x_e, x_e_bf);
        embed_pe_kernel<<<embed_blocks, 256, 0, stream>>>(dec, emb, x_d, x_d_bf);

        // ---------------- Encoder (6 layers) ----------------
        for (int l = 0; l < 6; ++l) {
            launch_mfma<4,false,false,false>(x_e_bf, wqkvb, nullptr, qkv, TOK, 3*EMB, EMB, stream);
            attn_tile_kernel<true><<<attn_grid, 256, 0, stream>>>(
                qkv,        3 * EMB, 3 * DK,
                qkv + DK,   3 * EMB, 3 * DK,
                qkv + 2*DK, 3 * EMB, 3 * DK,
                enc_mask, 0, ctxbf, SEQ, SEQ);
            launch_mfma<2,true,false,false>(ctxbf, wlinb, b_lin, tmpb, TOK, EMB, EMB, stream);
            add_ln_kernel<<<TOK, 256, 0, stream>>>(x_e, tmpb, ln_e1g, ln_e1b, x_e_bf);
            launch_mfma<4,true,true,true>(x_e_bf, wff1b, b_ff1, ffbf, TOK, FF, EMB, stream);
            launch_mfma<2,true,false,false>(ffbf, wff2b, b_ff2, tmpb, TOK, EMB, FF, stream);
            add_ln_kernel<<<TOK, 256, 0, stream>>>(x_e, tmpb, ln_e2g, ln_e2b, x_e_bf);
        }

        launch_mfma<4,false,false,false>(x_e_bf, wqkvb, nullptr, ekv, TOK, 3*EMB, EMB, stream);

        // ---------------- Decoder (6 layers) ----------------
        for (int l = 0; l < 6; ++l) {
            launch_mfma<4,false,false,false>(x_d_bf, wqkvb, nullptr, qkv, TOK, 3*EMB, EMB, stream);
            attn_tile_kernel<true><<<attn_grid, 256, 0, stream>>>(
                qkv,        3 * EMB, 3 * DK,
                qkv + DK,   3 * EMB, 3 * DK,
                qkv + 2*DK, 3 * EMB, 3 * DK,
                dec_mask, 1, ctxbf, SEQ, SEQ);
            launch_mfma<2,true,false,false>(ctxbf, wlinb, b_lin, tmpb, TOK, EMB, EMB, stream);
            add_ln_kernel<<<TOK, 256, 0, stream>>>(x_d, tmpb, ln_d1g, ln_d1b, x_d_bf);

            // cross-attention: dq = x_d @ w_qkv[:512].T  (dense [4096][512])
            launch_mfma<2,false,false,false>(x_d_bf, wqkvb, nullptr, qkv, TOK, EMB, EMB, stream);
            attn_tile_kernel<true><<<attn_grid, 256, 0, stream>>>(
                qkv,          EMB,     DK,
                ekv + DK,     3 * EMB, 3 * DK,
                ekv + 2*DK,   3 * EMB, 3 * DK,
                enc_mask, 0, ctxbf, SEQ, SEQ);
            launch_mfma<2,true,false,false>(ctxbf, wlinb, b_lin, tmpb, TOK, EMB, EMB, stream);
            add_ln_kernel<<<TOK, 256, 0, stream>>>(x_d, tmpb, ln_d2g, ln_d2b, x_d_bf);

            launch_mfma<4,true,true,true>(x_d_bf, wff1b, b_ff1, ffbf, TOK, FF, EMB, stream);
            launch_mfma<2,true,false,false>(ffbf, wff2b, b_ff2, tmpb, TOK, EMB, FF, stream);
            add_ln_kernel<<<TOK, 256, 0, stream>>>(x_d, tmpb, ln_d3g, ln_d3b, x_d_bf);
        }

        // ---------------- Output projection + softmax ----------------
        launch_mfma<4,true,false,false>(x_d_bf, woutb, b_out, out, TOK, VOCAB, EMB, stream);
        softmax_vocab_kernel<<<TOK, 256, 0, stream>>>(out);
        return;
    }

    // ---------------- Legacy f32 fallback (scratch in d_out) ----------------
    const size_t sz_x   = sz_xf;
    char* wsp = (char*)d_ws;
    float* x_d_buf = (float*)wsp;
    char* op = (char*)d_out;
    float* x_e  = (float*)op; op += sz_x;
    float* qkv  = (float*)op; op += sz_qkv;
    float* ekv  = (float*)op; op += sz_qkv;
    float* ctxb = (float*)op; op += sz_x;
    float* tmpb = (float*)op; op += sz_x;
    float* ffb  = (float*)op;

    embed_pe_kernel<<<embed_blocks, 256, 0, stream>>>(enc, emb, x_e, nullptr);
    embed_pe_kernel<<<embed_blocks, 256, 0, stream>>>(dec, emb, x_d_buf, nullptr);

    for (int l = 0; l < 6; ++l) {
        launch_gemm_f32(x_e, w_qkv, nullptr, qkv, TOK, 3 * EMB, EMB, false, stream);
        attn_tile_kernel<false><<<attn_grid, 256, 0, stream>>>(
            qkv,        3 * EMB, 3 * DK,
            qkv + DK,   3 * EMB, 3 * DK,
            qkv + 2*DK, 3 * EMB, 3 * DK,
            enc_mask, 0, ctxb, SEQ, SEQ);
        launch_gemm_f32(ctxb, w_lin, b_lin, tmpb, TOK, EMB, EMB, false, stream);
        add_ln_kernel<<<TOK, 256, 0, stream>>>(x_e, tmpb, ln_e1g, ln_e1b, nullptr);
        launch_gemm_f32(x_e, w_ff1, b_ff1, ffb, TOK, FF, EMB, true, stream);
        launch_gemm_f32(ffb, w_ff2, b_ff2, tmpb, TOK, EMB, FF, false, stream);
        add_ln_kernel<<<TOK, 256, 0, stream>>>(x_e, tmpb, ln_e2g, ln_e2b, nullptr);
    }

    launch_gemm_f32(x_e, w_qkv, nullptr, ekv, TOK, 3 * EMB, EMB, false, stream);

    for (int l = 0; l < 6; ++l) {
        launch_gemm_f32(x_d_buf, w_qkv, nullptr, qkv, TOK, 3 * EMB, EMB, false, stream);
        attn_tile_kernel<false><<<attn_grid, 256, 0, stream>>>(
            qkv,        3 * EMB, 3 * DK,
            qkv + DK,   3 * EMB, 3 * DK,
            qkv + 2*DK, 3 * EMB, 3 * DK,
            dec_mask, 1, ctxb, SEQ, SEQ);
        launch_gemm_f32(ctxb, w_lin, b_lin, tmpb, TOK, EMB, EMB, false, stream);
        add_ln_kernel<<<TOK, 256, 0, stream>>>(x_d_buf, tmpb, ln_d1g, ln_d1b, nullptr);

        launch_gemm_f32(x_d_buf, w_qkv, nullptr, qkv, TOK, EMB, EMB, false, stream);
        attn_tile_kernel<false><<<attn_grid, 256, 0, stream>>>(
            qkv,          EMB,     DK,
            ekv + DK,     3 * EMB, 3 * DK,
            ekv + 2*DK,   3 * EMB, 3 * DK,
            enc_mask, 0, ctxb, SEQ, SEQ);
        launch_gemm_f32(ctxb, w_lin, b_lin, tmpb, TOK, EMB, EMB, false, stream);
        add_ln_kernel<<<TOK, 256, 0, stream>>>(x_d_buf, tmpb, ln_d2g, ln_d2b, nullptr);

        launch_gemm_f32(x_d_buf, w_ff1, b_ff1, ffb, TOK, FF, EMB, true, stream);
        launch_gemm_f32(ffb, w_ff2, b_ff2, tmpb, TOK, EMB, FF, false, stream);
        add_ln_kernel<<<TOK, 256, 0, stream>>>(x_d_buf, tmpb, ln_d3g, ln_d3b, nullptr);
    }

    launch_gemm_f32(x_d_buf, w_out, b_out, out, TOK, VOCAB, EMB, false, stream);
    softmax_vocab_kernel<<<TOK, 256, 0, stream>>>(out);
}

// Round 5
// 3075.676 us; speedup vs baseline: 12.9614x; 1.6625x over previous
//
#include <hip/hip_runtime.h>
#include <cmath>

// Problem constants
#define BATCH 8
#define SEQ   512
#define EMB   512
#define HEADS 8
#define DK    64
#define FF    2048
#define VOCAB 32000
#define TOK   (BATCH * SEQ)   // 4096 rows
#define INV_SCALE 0.125f      // 1/sqrt(64)

typedef __attribute__((ext_vector_type(8))) short bf16x8;
typedef __attribute__((ext_vector_type(4))) float f32x4;

__device__ __forceinline__ unsigned short f2bf(float f) {
    unsigned int u = __float_as_uint(f);
    return (unsigned short)((u + 0x7FFFu + ((u >> 16) & 1u)) >> 16);
}

// async global->LDS, 16 B per lane (wave-uniform LDS base + lane*16)
__device__ __forceinline__ void gl_lds16(const void* g, void* l) {
    __builtin_amdgcn_global_load_lds(
        (const __attribute__((address_space(1))) void*)g,
        (__attribute__((address_space(3))) void*)l, 16, 0, 0);
}

// ---------------------------------------------------------------------------
// Embedding lookup + positional encoding; writes f32 and (optional) bf16 copy
// ---------------------------------------------------------------------------
__global__ __launch_bounds__(256) void embed_pe_kernel(
    const int* __restrict__ tok, const float* __restrict__ table,
    float* __restrict__ out, unsigned short* __restrict__ outbf)
{
    int idx = blockIdx.x * 256 + threadIdx.x;      // < TOK*EMB = 2M
    int d   = idx & (EMB - 1);
    int row = idx >> 9;                            // EMB = 512 = 2^9
    int s   = row & (SEQ - 1);                     // SEQ = 512
    float p   = powf(10000.0f, (2.0f * (float)d) * (1.0f / (float)EMB));
    float ang = (float)s / p;
    float pe  = ((d & 1) == 0) ? sinf(ang) : cosf(ang);
    float v   = table[(size_t)tok[row] * EMB + d] + pe;
    out[idx] = v;
    if (outbf) outbf[idx] = f2bf(v);
}

// ---------------------------------------------------------------------------
// f32 -> bf16 cast (RNE), 8 elements per thread. n8 = count/8.
// ---------------------------------------------------------------------------
__global__ __launch_bounds__(256) void cast_f32_to_bf16(
    const float* __restrict__ in, unsigned short* __restrict__ out, int n8)
{
    int i = blockIdx.x * 256 + threadIdx.x;
    if (i >= n8) return;
    const float4* p = (const float4*)(in + (size_t)i * 8);
    float4 f0 = p[0], f1 = p[1];
    float v[8] = {f0.x, f0.y, f0.z, f0.w, f1.x, f1.y, f1.z, f1.w};
    union { unsigned short u[8]; int4 v4; } r;
#pragma unroll
    for (int j = 0; j < 8; ++j) r.u[j] = f2bf(v[j]);
    *(int4*)(out + (size_t)i * 8) = r.v4;
}

// ---------------------------------------------------------------------------
// bf16 MFMA GEMM: C[M,N] = A[M,K] @ B[N,K]^T (+bias) (opt ReLU, f32/bf16 out)
// Tile 128 x (NF*32), BK=64, 256 threads = 4 waves 2x2, wave = 64 x (NF*16).
// Staging: global_load_lds width 16, LINEAR LDS + XOR-swizzled global source
// (kc ^= row&7); fragment ds_read_b128 applies the same XOR (rule #21).
// ---------------------------------------------------------------------------
template<int NF, bool HASBIAS, bool RELU, bool BF16OUT>
__global__ __launch_bounds__(256) void gemm_bf16_mfma(
    const unsigned short* __restrict__ A,   // [M][K] bf16
    const unsigned short* __restrict__ B,   // [N][K] bf16
    const float* __restrict__ bias,         // [N] or null
    void* __restrict__ Cout, int M, int N, int K)
{
    constexpr int BN   = NF * 32;
    constexpr int CH_A = 128 * 8;           // 16B chunks in A tile
    constexpr int CH_B = BN * 8;
    constexpr int NIT  = (CH_A + CH_B) / 256;

    __shared__ unsigned short As[128 * 64]; // linear, no pad (swizzled)
    __shared__ unsigned short Bs[BN * 64];

    const int tid  = threadIdx.x;
    const int m0   = blockIdx.y << 7;
    const int n0   = blockIdx.x * BN;
    const int wave = tid >> 6;
    const int lane = tid & 63;
    const int wch  = wave << 6;              // wave chunk base offset
    const int wm   = (wave >> 1) << 6;       // wave row offset
    const int wn   = (wave & 1) * (NF * 16); // wave col offset
    const int l15  = lane & 15;
    const int lg   = lane >> 4;              // 0..3

    f32x4 acc[4][NF] = {};

    for (int k0 = 0; k0 < K; k0 += 64) {
        __syncthreads();   // previous tile's fragment reads done
#pragma unroll
        for (int it = 0; it < NIT; ++it) {
            const int cb = it * 256 + wch;   // wave-uniform chunk base
            const int c  = cb + lane;        // this lane's chunk
            if (cb < CH_A) {
                const int row = c >> 3, kc = c & 7;
                gl_lds16(&A[(size_t)(m0 + row) * K + k0 + (kc ^ (row & 7)) * 8],
                         &As[(size_t)cb * 8]);
            } else {
                const int cc = c - CH_A, row = cc >> 3, kc = cc & 7;
                gl_lds16(&B[(size_t)(n0 + row) * K + k0 + (kc ^ (row & 7)) * 8],
                         &Bs[(size_t)(cb - CH_A) * 8]);
            }
        }
        __syncthreads();   // drains vmcnt (compiler-inserted)

#pragma unroll
        for (int ks = 0; ks < 2; ++ks) {
            const int kch = ks * 4 + lg;
            bf16x8 af[4], bfr[NF];
#pragma unroll
            for (int mi = 0; mi < 4; ++mi) {
                const int row = wm + mi * 16 + l15;
                af[mi] = *(const bf16x8*)&As[row * 64 + ((kch ^ (row & 7)) << 3)];
            }
#pragma unroll
            for (int ni = 0; ni < NF; ++ni) {
                const int row = wn + ni * 16 + l15;
                bfr[ni] = *(const bf16x8*)&Bs[row * 64 + ((kch ^ (row & 7)) << 3)];
            }
#pragma unroll
            for (int mi = 0; mi < 4; ++mi)
#pragma unroll
                for (int ni = 0; ni < NF; ++ni)
                    acc[mi][ni] = __builtin_amdgcn_mfma_f32_16x16x32_bf16(
                        af[mi], bfr[ni], acc[mi][ni], 0, 0, 0);
        }
    }

    // C/D layout: col = lane&15 (N), row = (lane>>4)*4 + r (M)
#pragma unroll
    for (int mi = 0; mi < 4; ++mi) {
        const int mb = m0 + wm + mi * 16 + lg * 4;
#pragma unroll
        for (int ni = 0; ni < NF; ++ni) {
            const int n = n0 + wn + ni * 16 + l15;
            const float bv = HASBIAS ? bias[n] : 0.0f;
#pragma unroll
            for (int r = 0; r < 4; ++r) {
                float v = acc[mi][ni][r] + bv;
                if (RELU) v = fmaxf(v, 0.0f);
                if (BF16OUT)
                    ((unsigned short*)Cout)[(size_t)(mb + r) * N + n] = f2bf(v);
                else
                    ((float*)Cout)[(size_t)(mb + r) * N + n] = v;
            }
        }
    }
}

template<int NF, bool HB, bool RL, bool BO>
static inline void launch_mfma(const unsigned short* A, const unsigned short* B,
                               const float* bias, void* C, int M, int N, int K,
                               hipStream_t s)
{
    dim3 grid((unsigned)(N / (NF * 32)), (unsigned)(M / 128));
    gemm_bf16_mfma<NF, HB, RL, BO><<<grid, 256, 0, s>>>(A, B, bias, C, M, N, K);
}

// ---------------------------------------------------------------------------
// bf16 MFMA flash attention. One block per (b, h, 64-q-tile); 4 waves, each
// owns 16 q-rows. K tile LDS is aliased as the P buffer after QK^T.
// ---------------------------------------------------------------------------
__global__ __launch_bounds__(256) void attn_bf16_mfma(
    const unsigned short* __restrict__ Qb, int q_rs, int q_hs,
    const unsigned short* __restrict__ Kb, int k_rs, int k_hs,
    const unsigned short* __restrict__ Vb, int v_rs, int v_hs,
    const float* __restrict__ addmask, int causal,
    unsigned short* __restrict__ ctx, int SQ, int SK)
{
    const int qt = blockIdx.x, h = blockIdx.y, b = blockIdx.z;
    const int t  = threadIdx.x;
    const int q0 = qt << 6;

    __shared__ unsigned short sQ [64][72];   // [q][d]   (72*2=144B rows, 16B-aligned)
    __shared__ unsigned short sK [64][72];   // [k][d], then P [q][k]
    __shared__ unsigned short sVT[64][72];   // [d][k]

    const int lane = t & 63;
    const int wv   = t >> 6;        // wave 0..3
    const int qw   = wv << 4;       // wave's q base within tile
    const int l15  = lane & 15;
    const int lg   = lane >> 4;     // 0..3

    // ---- stage Q tile (once) ----
#pragma unroll
    for (int u = 0; u < 2; ++u) {
        int c = u * 256 + t, row = c >> 3, kc = c & 7;
        *(int4*)&sQ[row][kc * 8] =
            *(const int4*)(Qb + (size_t)(b * SQ + q0 + row) * q_rs + h * q_hs + kc * 8);
    }

    float M[4], L[4];
    f32x4 o[4] = {};
#pragma unroll
    for (int r = 0; r < 4; ++r) { M[r] = -INFINITY; L[r] = 0.0f; }

    const int nkt = causal ? (qt + 1) : (SK >> 6);

    for (int kt = 0; kt < nkt; ++kt) {
        const int k0 = kt << 6;
        __syncthreads();   // prior PV reads of sK/sVT done
        // ---- stage K tile + V^T tile ----
#pragma unroll
        for (int u = 0; u < 2; ++u) {
            int c = u * 256 + t, row = c >> 3, kc = c & 7;
            *(int4*)&sK[row][kc * 8] =
                *(const int4*)(Kb + (size_t)(b * SK + k0 + row) * k_rs + h * k_hs + kc * 8);
            union { int4 v; unsigned short us[8]; } vv;
            vv.v = *(const int4*)(Vb + (size_t)(b * SK + k0 + row) * v_rs + h * v_hs + kc * 8);
#pragma unroll
            for (int j = 0; j < 8; ++j) sVT[kc * 8 + j][row] = vv.us[j];
        }
        __syncthreads();

        // ---- QK^T: S[16][64] per wave (4 col-frags x 2 k-chunks) ----
        f32x4 sc[4] = {};
#pragma unroll
        for (int c = 0; c < 2; ++c) {
            bf16x8 qa = *(const bf16x8*)&sQ[qw + l15][c * 32 + lg * 8];
#pragma unroll
            for (int f = 0; f < 4; ++f) {
                bf16x8 kb = *(const bf16x8*)&sK[f * 16 + l15][c * 32 + lg * 8];
                sc[f] = __builtin_amdgcn_mfma_f32_16x16x32_bf16(qa, kb, sc[f], 0, 0, 0);
            }
        }

        // ---- scale + mask (C layout: row=lg*4+r, col=f*16+l15) ----
#pragma unroll
        for (int f = 0; f < 4; ++f) {
            const int k = k0 + f * 16 + l15;
            const float m = addmask ? addmask[(size_t)b * SK + k] : 0.0f;
#pragma unroll
            for (int r = 0; r < 4; ++r) {
                float sv = (sc[f][r] + m) * INV_SCALE;
                if (causal && k > q0 + qw + lg * 4 + r) sv = -INFINITY;
                sc[f][r] = sv;
            }
        }

        // ---- row max across 16 lanes of the lg-group ----
        float mx[4];
#pragma unroll
        for (int r = 0; r < 4; ++r)
            mx[r] = fmaxf(fmaxf(sc[0][r], sc[1][r]), fmaxf(sc[2][r], sc[3][r]));
#pragma unroll
        for (int off = 1; off < 16; off <<= 1)
#pragma unroll
            for (int r = 0; r < 4; ++r)
                mx[r] = fmaxf(mx[r], __shfl_xor(mx[r], off, 64));

        float al[4], rsum[4];
#pragma unroll
        for (int r = 0; r < 4; ++r) {
            const float Mn = fmaxf(M[r], mx[r]);
            al[r] = expf(M[r] - Mn);   // first tile: exp(-inf)=0
            M[r]  = Mn;
            rsum[r] = 0.0f;
        }

        __syncthreads();   // all QK^T reads of sK done; safe to overwrite as P
        // ---- exp, P->LDS bf16 (alias sK), partial row sums ----
#pragma unroll
        for (int f = 0; f < 4; ++f)
#pragma unroll
            for (int r = 0; r < 4; ++r) {
                const float p = expf(sc[f][r] - M[r]);   // -inf -> 0
                rsum[r] += p;
                sK[qw + lg * 4 + r][f * 16 + l15] = f2bf(p);
            }
#pragma unroll
        for (int off = 1; off < 16; off <<= 1)
#pragma unroll
            for (int r = 0; r < 4; ++r)
                rsum[r] += __shfl_xor(rsum[r], off, 64);
#pragma unroll
        for (int r = 0; r < 4; ++r) L[r] = L[r] * al[r] + rsum[r];
#pragma unroll
        for (int f = 0; f < 4; ++f)
#pragma unroll
            for (int r = 0; r < 4; ++r) o[f][r] *= al[r];
        __syncthreads();   // P writes visible

        // ---- PV: O[16][64] per wave; A=P[q][k], B=V^T[d][k] ----
#pragma unroll
        for (int c = 0; c < 2; ++c) {
            bf16x8 pa = *(const bf16x8*)&sK[qw + l15][c * 32 + lg * 8];
#pragma unroll
            for (int f = 0; f < 4; ++f) {
                bf16x8 vb = *(const bf16x8*)&sVT[f * 16 + l15][c * 32 + lg * 8];
                o[f] = __builtin_amdgcn_mfma_f32_16x16x32_bf16(pa, vb, o[f], 0, 0, 0);
            }
        }
    }

    // ---- epilogue: ctx bf16 ----
#pragma unroll
    for (int r = 0; r < 4; ++r) {
        const float inv = 1.0f / L[r];
        const int q = q0 + qw + lg * 4 + r;
#pragma unroll
        for (int f = 0; f < 4; ++f)
            ctx[(size_t)(b * SQ + q) * EMB + h * DK + f * 16 + l15] =
                f2bf(o[f][r] * inv);
    }
}

// ---------------------------------------------------------------------------
// Legacy f32 GEMM + attention (fallback path only)
// ---------------------------------------------------------------------------
template<bool HASBIAS, bool RELU>
__global__ __launch_bounds__(256) void gemm_tn(
    const float* __restrict__ A, const float* __restrict__ W,
    const float* __restrict__ bias, float* __restrict__ C,
    int M, int N, int K)
{
    __shared__ float As[16][64];
    __shared__ float Bs[16][64];
    const int tid = threadIdx.x;
    const int tx  = tid & 15;
    const int ty  = tid >> 4;
    const int m0  = blockIdx.y << 6;
    const int n0  = blockIdx.x << 6;
    const int lrow = tid >> 2;
    const int lcol = (tid & 3) << 2;

    const float* Aload = A + (size_t)(m0 + lrow) * K + lcol;
    const float* Wload = W + (size_t)(n0 + lrow) * K + lcol;

    float acc[4][4] = {};

    for (int k0 = 0; k0 < K; k0 += 16) {
        float4 a4 = *(const float4*)(Aload + k0);
        float4 w4 = *(const float4*)(Wload + k0);
        As[lcol + 0][lrow] = a4.x; As[lcol + 1][lrow] = a4.y;
        As[lcol + 2][lrow] = a4.z; As[lcol + 3][lrow] = a4.w;
        Bs[lcol + 0][lrow] = w4.x; Bs[lcol + 1][lrow] = w4.y;
        Bs[lcol + 2][lrow] = w4.z; Bs[lcol + 3][lrow] = w4.w;
        __syncthreads();
#pragma unroll
        for (int kk = 0; kk < 16; ++kk) {
            float4 av = *(const float4*)&As[kk][ty << 2];
            float4 bv = *(const float4*)&Bs[kk][tx << 2];
            float a[4] = {av.x, av.y, av.z, av.w};
            float b[4] = {bv.x, bv.y, bv.z, bv.w};
#pragma unroll
            for (int i = 0; i < 4; ++i)
#pragma unroll
                for (int j = 0; j < 4; ++j)
                    acc[i][j] = fmaf(a[i], b[j], acc[i][j]);
        }
        __syncthreads();
    }

#pragma unroll
    for (int i = 0; i < 4; ++i) {
        const int m = m0 + (ty << 2) + i;
#pragma unroll
        for (int j = 0; j < 4; ++j) {
            const int n = n0 + (tx << 2) + j;
            float v = acc[i][j];
            if (HASBIAS) v += bias[n];
            if (RELU)    v = fmaxf(v, 0.0f);
            C[(size_t)m * N + n] = v;
        }
    }
}

__global__ __launch_bounds__(256) void attn_tile_f32(
    const float* __restrict__ Qb, int q_rs, int q_hs,
    const float* __restrict__ Kb, int k_rs, int k_hs,
    const float* __restrict__ Vb, int v_rs, int v_hs,
    const float* __restrict__ addmask, int causal,
    float* __restrict__ ctx, int SQ, int SK)
{
    const int qt = blockIdx.x, h = blockIdx.y, b = blockIdx.z;
    const int t  = threadIdx.x;
    const int q0 = qt << 6;

    __shared__ float sQT[64][68];
    __shared__ float sKP[64][68];
    __shared__ float sV [64][68];

    const int lr = t & 63;
    const int dc = (t >> 6) << 4;

    {
        const float* Qrow = Qb + (size_t)(b * SQ + q0 + lr) * q_rs + h * q_hs + dc;
#pragma unroll
        for (int u = 0; u < 4; ++u) {
            float4 v = *(const float4*)(Qrow + u * 4);
            sQT[dc + u * 4 + 0][lr] = v.x;
            sQT[dc + u * 4 + 1][lr] = v.y;
            sQT[dc + u * 4 + 2][lr] = v.z;
            sQT[dc + u * 4 + 3][lr] = v.w;
        }
    }

    const int tx = t & 15;
    const int ty = t >> 4;

    float M[4], L[4], o[4][4];
#pragma unroll
    for (int i = 0; i < 4; ++i) {
        M[i] = -INFINITY; L[i] = 0.0f;
#pragma unroll
        for (int j = 0; j < 4; ++j) o[i][j] = 0.0f;
    }

    const int nkt = causal ? (qt + 1) : (SK >> 6);

    for (int kt = 0; kt < nkt; ++kt) {
        const int k0 = kt << 6;
        __syncthreads();
        {
            const float* Krow = Kb + (size_t)(b * SK + k0 + lr) * k_rs + h * k_hs + dc;
            const float* Vrow = Vb + (size_t)(b * SK + k0 + lr) * v_rs + h * v_hs + dc;
#pragma unroll
            for (int u = 0; u < 4; ++u) {
                float4 kv = *(const float4*)(Krow + u * 4);
                sKP[dc + u * 4 + 0][lr] = kv.x;
                sKP[dc + u * 4 + 1][lr] = kv.y;
                sKP[dc + u * 4 + 2][lr] = kv.z;
                sKP[dc + u * 4 + 3][lr] = kv.w;
                *(float4*)&sV[lr][dc + u * 4] = *(const float4*)(Vrow + u * 4);
            }
        }
        __syncthreads();

        float s[4][4] = {};
#pragma unroll 16
        for (int d = 0; d < 64; ++d) {
            float4 aq = *(const float4*)&sQT[d][ty << 2];
            float4 bk = *(const float4*)&sKP[d][tx << 2];
            float a[4] = {aq.x, aq.y, aq.z, aq.w};
            float bb[4] = {bk.x, bk.y, bk.z, bk.w};
#pragma unroll
            for (int i = 0; i < 4; ++i)
#pragma unroll
                for (int j = 0; j < 4; ++j)
                    s[i][j] = fmaf(a[i], bb[j], s[i][j]);
        }

#pragma unroll
        for (int j = 0; j < 4; ++j) {
            const int k = k0 + (tx << 2) + j;
            const float m = addmask ? addmask[(size_t)b * SK + k] : 0.0f;
#pragma unroll
            for (int i = 0; i < 4; ++i) {
                float sv = (s[i][j] + m) * INV_SCALE;
                if (causal && k > q0 + (ty << 2) + i) sv = -INFINITY;
                s[i][j] = sv;
            }
        }

        float mx[4];
#pragma unroll
        for (int i = 0; i < 4; ++i)
            mx[i] = fmaxf(fmaxf(s[i][0], s[i][1]), fmaxf(s[i][2], s[i][3]));
#pragma unroll
        for (int off = 1; off < 16; off <<= 1) {
#pragma unroll
            for (int i = 0; i < 4; ++i)
                mx[i] = fmaxf(mx[i], __shfl_xor(mx[i], off, 64));
        }

        float al[4];
#pragma unroll
        for (int i = 0; i < 4; ++i) {
            const float Mn = fmaxf(M[i], mx[i]);
            al[i] = expf(M[i] - Mn);
            M[i]  = Mn;
        }
        float rs[4] = {};
#pragma unroll
        for (int i = 0; i < 4; ++i) {
#pragma unroll
            for (int j = 0; j < 4; ++j) {
                const float p = expf(s[i][j] - M[i]);
                s[i][j] = p;
                rs[i] += p;
            }
        }
#pragma unroll
        for (int off = 1; off < 16; off <<= 1) {
#pragma unroll
            for (int i = 0; i < 4; ++i)
                rs[i] += __shfl_xor(rs[i], off, 64);
        }
#pragma unroll
        for (int i = 0; i < 4; ++i) {
            L[i] = L[i] * al[i] + rs[i];
#pragma unroll
            for (int j = 0; j < 4; ++j) o[i][j] *= al[i];
        }

        __syncthreads();
#pragma unroll
        for (int j = 0; j < 4; ++j)
#pragma unroll
            for (int i = 0; i < 4; ++i)
                sKP[(tx << 2) + j][(ty << 2) + i] = s[i][j];
        __syncthreads();

#pragma unroll 16
        for (int kk = 0; kk < 64; ++kk) {
            float4 pa = *(const float4*)&sKP[kk][ty << 2];
            float4 vb = *(const float4*)&sV[kk][tx << 2];
            float a[4] = {pa.x, pa.y, pa.z, pa.w};
            float bb[4] = {vb.x, vb.y, vb.z, vb.w};
#pragma unroll
            for (int i = 0; i < 4; ++i)
#pragma unroll
                for (int j = 0; j < 4; ++j)
                    o[i][j] = fmaf(a[i], bb[j], o[i][j]);
        }
    }

#pragma unroll
    for (int i = 0; i < 4; ++i) {
        const float inv = 1.0f / L[i];
        float4 w;
        w.x = o[i][0] * inv; w.y = o[i][1] * inv;
        w.z = o[i][2] * inv; w.w = o[i][3] * inv;
        const int q = q0 + (ty << 2) + i;
        *(float4*)&ctx[(size_t)(b * SQ + q) * EMB + h * DK + (tx << 2)] = w;
    }
}

// ---------------------------------------------------------------------------
// x = LayerNorm(x + delta) * g + b ; optionally writes bf16 copy of result
// ---------------------------------------------------------------------------
__global__ __launch_bounds__(256) void add_ln_kernel(
    float* __restrict__ x, const float* __restrict__ delta,
    const float* __restrict__ g, const float* __restrict__ b,
    unsigned short* __restrict__ xbf)
{
    const int row = blockIdx.x;
    const int t = threadIdx.x;
    __shared__ float red[256];
    const size_t base = (size_t)row * EMB;

    float v0 = x[base + t]       + delta[base + t];
    float v1 = x[base + 256 + t] + delta[base + 256 + t];

    red[t] = v0 + v1; __syncthreads();
    for (int o = 128; o > 0; o >>= 1) {
        if (t < o) red[t] += red[t + o];
        __syncthreads();
    }
    const float mean = red[0] * (1.0f / (float)EMB);
    __syncthreads();

    const float a0 = v0 - mean, a1 = v1 - mean;
    red[t] = a0 * a0 + a1 * a1; __syncthreads();
    for (int o = 128; o > 0; o >>= 1) {
        if (t < o) red[t] += red[t + o];
        __syncthreads();
    }
    const float inv = 1.0f / sqrtf(red[0] * (1.0f / (float)EMB) + 1e-5f);

    const float r0 = a0 * inv * g[t]       + b[t];
    const float r1 = a1 * inv * g[256 + t] + b[256 + t];
    x[base + t]       = r0;
    x[base + 256 + t] = r1;
    if (xbf) {
        xbf[base + t]       = f2bf(r0);
        xbf[base + 256 + t] = f2bf(r1);
    }
}

// ---------------------------------------------------------------------------
// Row softmax over VOCAB (in place), float4-vectorized. One block per row.
// ---------------------------------------------------------------------------
__global__ __launch_bounds__(256) void softmax_vocab_kernel(float* __restrict__ X)
{
    const int row = blockIdx.x;
    const int t = threadIdx.x;
    __shared__ float rm[256], rs[256];
    float4* x4 = (float4*)(X + (size_t)row * VOCAB);
    const int N4 = VOCAB / 4;   // 8000

    float m = -INFINITY, s = 0.0f;
    for (int c = t; c < N4; c += 256) {
        float4 v = x4[c];
        float lm = fmaxf(fmaxf(v.x, v.y), fmaxf(v.z, v.w));
        if (lm > m) { s *= expf(m - lm); m = lm; }
        s += expf(v.x - m) + expf(v.y - m) + expf(v.z - m) + expf(v.w - m);
    }
    rm[t] = m; rs[t] = s; __syncthreads();
    for (int o = 128; o > 0; o >>= 1) {
        if (t < o) {
            float m1 = rm[t], m2 = rm[t + o];
            float s1 = rs[t], s2 = rs[t + o];
            float MM = fmaxf(m1, m2);
            rs[t] = s1 * expf(m1 - MM) + s2 * expf(m2 - MM);
            rm[t] = MM;
        }
        __syncthreads();
    }
    const float M = rm[0];
    const float inv = 1.0f / rs[0];
    for (int c = t; c < N4; c += 256) {
        float4 v = x4[c];
        v.x = expf(v.x - M) * inv; v.y = expf(v.y - M) * inv;
        v.z = expf(v.z - M) * inv; v.w = expf(v.w - M) * inv;
        x4[c] = v;
    }
}

// ---------------------------------------------------------------------------
// Host orchestration
// ---------------------------------------------------------------------------
static inline void launch_gemm_f32(const float* A, const float* W, const float* bias,
                                   float* C, int M, int N, int K, bool relu,
                                   hipStream_t stream)
{
    dim3 grid((unsigned)(N / 64), (unsigned)(M / 64));
    if (bias) {
        if (relu) gemm_tn<true, true ><<<grid, 256, 0, stream>>>(A, W, bias, C, M, N, K);
        else      gemm_tn<true, false><<<grid, 256, 0, stream>>>(A, W, bias, C, M, N, K);
    } else {
        gemm_tn<false, false><<<grid, 256, 0, stream>>>(A, W, nullptr, C, M, N, K);
    }
}

extern "C" void kernel_launch(void* const* d_in, const int* in_sizes, int n_in,
                              void* d_out, int out_size, void* d_ws, size_t ws_size,
                              hipStream_t stream)
{
    const int*   enc      = (const int*)  d_in[0];
    const int*   dec      = (const int*)  d_in[1];
    const float* enc_mask = (const float*)d_in[2];
    const float* dec_mask = (const float*)d_in[3];
    const float* emb    = (const float*)d_in[6];
    const float* w_qkv  = (const float*)d_in[7];
    const float* w_lin  = (const float*)d_in[8];
    const float* b_lin  = (const float*)d_in[9];
    const float* w_ff1  = (const float*)d_in[10];
    const float* b_ff1  = (const float*)d_in[11];
    const float* w_ff2  = (const float*)d_in[12];
    const float* b_ff2  = (const float*)d_in[13];
    const float* w_out  = (const float*)d_in[14];
    const float* b_out  = (const float*)d_in[15];
    const float* ln_e1g = (const float*)d_in[16];
    const float* ln_e1b = (const float*)d_in[17];
    const float* ln_e2g = (const float*)d_in[18];
    const float* ln_e2b = (const float*)d_in[19];
    const float* ln_d1g = (const float*)d_in[20];
    const float* ln_d1b = (const float*)d_in[21];
    const float* ln_d2g = (const float*)d_in[22];
    const float* ln_d2b = (const float*)d_in[23];
    const float* ln_d3g = (const float*)d_in[24];
    const float* ln_d3b = (const float*)d_in[25];

    float* out = (float*)d_out;

    const size_t sz_xf    = (size_t)TOK * EMB * sizeof(float);     // 8 MB
    const size_t sz_xbf   = (size_t)TOK * EMB * 2;                 // 4 MB
    const size_t sz_qkvbf = (size_t)TOK * 3 * EMB * 2;             // 12.6 MB
    const size_t sz_tmp   = sz_xf;
    const size_t sz_ffbf  = (size_t)TOK * FF * 2;                  // 16.8 MB
    const size_t sz_wqkv  = (size_t)3 * EMB * EMB * 2;
    const size_t sz_wlin  = (size_t)EMB * EMB * 2;
    const size_t sz_wff1  = (size_t)FF * EMB * 2;
    const size_t sz_wff2  = (size_t)EMB * FF * 2;
    const size_t sz_wout  = (size_t)VOCAB * EMB * 2;               // 32.8 MB
    const size_t need_bf = 2 * (sz_xf + sz_xbf) + 2 * sz_qkvbf + sz_xbf + sz_tmp +
                           sz_ffbf + sz_wqkv + sz_wlin + sz_wff1 + sz_wff2 + sz_wout;

    const dim3 attn_grid(SEQ / 64, HEADS, BATCH);   // (8, 8, 8)
    const int  embed_blocks = (TOK * EMB) / 256;

    if (ws_size >= need_bf) {
        // ---------------- bf16-MFMA main path ----------------
        char* p = (char*)d_ws;
        float* x_e             = (float*)p;          p += sz_xf;
        float* x_d             = (float*)p;          p += sz_xf;
        unsigned short* x_e_bf = (unsigned short*)p; p += sz_xbf;
        unsigned short* x_d_bf = (unsigned short*)p; p += sz_xbf;
        unsigned short* qkv_bf = (unsigned short*)p; p += sz_qkvbf;
        unsigned short* ekv_bf = (unsigned short*)p; p += sz_qkvbf;
        unsigned short* ctxbf  = (unsigned short*)p; p += sz_xbf;
        float* tmpb            = (float*)p;          p += sz_tmp;
        unsigned short* ffbf   = (unsigned short*)p; p += sz_ffbf;
        unsigned short* wqkvb  = (unsigned short*)p; p += sz_wqkv;
        unsigned short* wlinb  = (unsigned short*)p; p += sz_wlin;
        unsigned short* wff1b  = (unsigned short*)p; p += sz_wff1;
        unsigned short* wff2b  = (unsigned short*)p; p += sz_wff2;
        unsigned short* woutb  = (unsigned short*)p;

        // weight casts (once per launch)
        cast_f32_to_bf16<<<(3*EMB*EMB/8)/256, 256, 0, stream>>>(w_qkv, wqkvb, 3*EMB*EMB/8);
        cast_f32_to_bf16<<<(EMB*EMB/8)/256,   256, 0, stream>>>(w_lin, wlinb, EMB*EMB/8);
        cast_f32_to_bf16<<<(FF*EMB/8)/256,    256, 0, stream>>>(w_ff1, wff1b, FF*EMB/8);
        cast_f32_to_bf16<<<(EMB*FF/8)/256,    256, 0, stream>>>(w_ff2, wff2b, EMB*FF/8);
        cast_f32_to_bf16<<<(VOCAB*EMB/8)/256, 256, 0, stream>>>(w_out, woutb, VOCAB*EMB/8);

        embed_pe_kernel<<<embed_blocks, 256, 0, stream>>>(enc, emb, x_e, x_e_bf);
        embed_pe_kernel<<<embed_blocks, 256, 0, stream>>>(dec, emb, x_d, x_d_bf);

        // ---------------- Encoder (6 layers) ----------------
        for (int l = 0; l < 6; ++l) {
            launch_mfma<4,false,false,true>(x_e_bf, wqkvb, nullptr, qkv_bf, TOK, 3*EMB, EMB, stream);
            attn_bf16_mfma<<<attn_grid, 256, 0, stream>>>(
                qkv_bf,          3 * EMB, 3 * DK,
                qkv_bf + DK,     3 * EMB, 3 * DK,
                qkv_bf + 2*DK,   3 * EMB, 3 * DK,
                enc_mask, 0, ctxbf, SEQ, SEQ);
            launch_mfma<2,true,false,false>(ctxbf, wlinb, b_lin, tmpb, TOK, EMB, EMB, stream);
            add_ln_kernel<<<TOK, 256, 0, stream>>>(x_e, tmpb, ln_e1g, ln_e1b, x_e_bf);
            launch_mfma<4,true,true,true>(x_e_bf, wff1b, b_ff1, ffbf, TOK, FF, EMB, stream);
            launch_mfma<2,true,false,false>(ffbf, wff2b, b_ff2, tmpb, TOK, EMB, FF, stream);
            add_ln_kernel<<<TOK, 256, 0, stream>>>(x_e, tmpb, ln_e2g, ln_e2b, x_e_bf);
        }

        launch_mfma<4,false,false,true>(x_e_bf, wqkvb, nullptr, ekv_bf, TOK, 3*EMB, EMB, stream);

        // ---------------- Decoder (6 layers) ----------------
        for (int l = 0; l < 6; ++l) {
            launch_mfma<4,false,false,true>(x_d_bf, wqkvb, nullptr, qkv_bf, TOK, 3*EMB, EMB, stream);
            attn_bf16_mfma<<<attn_grid, 256, 0, stream>>>(
                qkv_bf,          3 * EMB, 3 * DK,
                qkv_bf + DK,     3 * EMB, 3 * DK,
                qkv_bf + 2*DK,   3 * EMB, 3 * DK,
                dec_mask, 1, ctxbf, SEQ, SEQ);
            launch_mfma<2,true,false,false>(ctxbf, wlinb, b_lin, tmpb, TOK, EMB, EMB, stream);
            add_ln_kernel<<<TOK, 256, 0, stream>>>(x_d, tmpb, ln_d1g, ln_d1b, x_d_bf);

            // cross-attention: dq = x_d @ w_qkv[:512].T  -> bf16 [4096][512]
            launch_mfma<2,false,false,true>(x_d_bf, wqkvb, nullptr, qkv_bf, TOK, EMB, EMB, stream);
            attn_bf16_mfma<<<attn_grid, 256, 0, stream>>>(
                qkv_bf,          EMB,     DK,
                ekv_bf + DK,     3 * EMB, 3 * DK,
                ekv_bf + 2*DK,   3 * EMB, 3 * DK,
                enc_mask, 0, ctxbf, SEQ, SEQ);
            launch_mfma<2,true,false,false>(ctxbf, wlinb, b_lin, tmpb, TOK, EMB, EMB, stream);
            add_ln_kernel<<<TOK, 256, 0, stream>>>(x_d, tmpb, ln_d2g, ln_d2b, x_d_bf);

            launch_mfma<4,true,true,true>(x_d_bf, wff1b, b_ff1, ffbf, TOK, FF, EMB, stream);
            launch_mfma<2,true,false,false>(ffbf, wff2b, b_ff2, tmpb, TOK, EMB, FF, stream);
            add_ln_kernel<<<TOK, 256, 0, stream>>>(x_d, tmpb, ln_d3g, ln_d3b, x_d_bf);
        }

        // ---------------- Output projection + softmax ----------------
        launch_mfma<4,true,false,false>(x_d_bf, woutb, b_out, out, TOK, VOCAB, EMB, stream);
        softmax_vocab_kernel<<<TOK, 256, 0, stream>>>(out);
        return;
    }

    // ---------------- Legacy f32 fallback (scratch in d_out) ----------------
    const size_t sz_qkvf = (size_t)TOK * 3 * EMB * sizeof(float);
    char* wsp = (char*)d_ws;
    float* x_d_buf = (float*)wsp;
    char* op = (char*)d_out;
    float* x_e  = (float*)op; op += sz_xf;
    float* qkv  = (float*)op; op += sz_qkvf;
    float* ekv  = (float*)op; op += sz_qkvf;
    float* ctxb = (float*)op; op += sz_xf;
    float* tmpb = (float*)op; op += sz_xf;
    float* ffb  = (float*)op;

    embed_pe_kernel<<<embed_blocks, 256, 0, stream>>>(enc, emb, x_e, nullptr);
    embed_pe_kernel<<<embed_blocks, 256, 0, stream>>>(dec, emb, x_d_buf, nullptr);

    for (int l = 0; l < 6; ++l) {
        launch_gemm_f32(x_e, w_qkv, nullptr, qkv, TOK, 3 * EMB, EMB, false, stream);
        attn_tile_f32<<<attn_grid, 256, 0, stream>>>(
            qkv,        3 * EMB, 3 * DK,
            qkv + DK,   3 * EMB, 3 * DK,
            qkv + 2*DK, 3 * EMB, 3 * DK,
            enc_mask, 0, ctxb, SEQ, SEQ);
        launch_gemm_f32(ctxb, w_lin, b_lin, tmpb, TOK, EMB, EMB, false, stream);
        add_ln_kernel<<<TOK, 256, 0, stream>>>(x_e, tmpb, ln_e1g, ln_e1b, nullptr);
        launch_gemm_f32(x_e, w_ff1, b_ff1, ffb, TOK, FF, EMB, true, stream);
        launch_gemm_f32(ffb, w_ff2, b_ff2, tmpb, TOK, EMB, FF, false, stream);
        add_ln_kernel<<<TOK, 256, 0, stream>>>(x_e, tmpb, ln_e2g, ln_e2b, nullptr);
    }

    launch_gemm_f32(x_e, w_qkv, nullptr, ekv, TOK, 3 * EMB, EMB, false, stream);

    for (int l = 0; l < 6; ++l) {
        launch_gemm_f32(x_d_buf, w_qkv, nullptr, qkv, TOK, 3 * EMB, EMB, false, stream);
        attn_tile_f32<<<attn_grid, 256, 0, stream>>>(
            qkv,        3 * EMB, 3 * DK,
            qkv + DK,   3 * EMB, 3 * DK,
            qkv + 2*DK, 3 * EMB, 3 * DK,
            dec_mask, 1, ctxb, SEQ, SEQ);
        launch_gemm_f32(ctxb, w_lin, b_lin, tmpb, TOK, EMB, EMB, false, stream);
        add_ln_kernel<<<TOK, 256, 0, stream>>>(x_d_buf, tmpb, ln_d1g, ln_d1b, nullptr);

        launch_gemm_f32(x_d_buf, w_qkv, nullptr, qkv, TOK, EMB, EMB, false, stream);
        attn_tile_f32<<<attn_grid, 256, 0, stream>>>(
            qkv,          EMB,     DK,
            ekv + DK,     3 * EMB, 3 * DK,
            ekv + 2*DK,   3 * EMB, 3 * DK,
            enc_mask, 0, ctxb, SEQ, SEQ);
        launch_gemm_f32(ctxb, w_lin, b_lin, tmpb, TOK, EMB, EMB, false, stream);
        add_ln_kernel<<<TOK, 256, 0, stream>>>(x_d_buf, tmpb, ln_d2g, ln_d2b, nullptr);

        launch_gemm_f32(x_d_buf, w_ff1, b_ff1, ffb, TOK, FF, EMB, true, stream);
        launch_gemm_f32(ffb, w_ff2, b_ff2, tmpb, TOK, EMB, FF, false, stream);
        add_ln_kernel<<<TOK, 256, 0, stream>>>(x_d_buf, tmpb, ln_d3g, ln_d3b, nullptr);
    }

    launch_gemm_f32(x_d_buf, w_out, b_out, out, TOK, VOCAB, EMB, false, stream);
    softmax_vocab_kernel<<<TOK, 256, 0, stream>>>(out);
}